// Round 3
// baseline (5493.133 us; speedup 1.0000x reference)
//
#include <hip/hip_runtime.h>

#define BB 256
#define TT 512
#define DD 200

// ---------- helpers ----------
__device__ __forceinline__ float bf2f(unsigned short u) {
    return __uint_as_float(((unsigned int)u) << 16);
}
__device__ __forceinline__ unsigned short f2bf(float f) {
    unsigned int u = __float_as_uint(f);
    u += 0x7FFFu + ((u >> 16) & 1u);
    return (unsigned short)(u >> 16);
}
__device__ __forceinline__ float sigm(float x) { return 1.0f / (1.0f + __expf(-x)); }
__device__ __forceinline__ float tanh_(float x) { return 1.0f - 2.0f / (__expf(2.0f * x) + 1.0f); }

typedef __bf16 bf16x8 __attribute__((ext_vector_type(8)));
typedef float  f32x4  __attribute__((ext_vector_type(4)));

#define GPAD 20

// async global->LDS 16B (dest = wave-uniform base + lane*16)
__device__ __forceinline__ void gll16(const unsigned short* g, unsigned short* l) {
    __builtin_amdgcn_global_load_lds(
        (const __attribute__((address_space(1))) unsigned int*)g,
        (__attribute__((address_space(3))) unsigned int*)l,
        16, 0, 0);
}

#define MAC16(ACCV, BASE, W) do { \
    const float4* _p4 = (const float4*)(BASE); \
    float4 _v0 = _p4[0], _v1 = _p4[1], _v2 = _p4[2], _v3 = _p4[3]; \
    ACCV[0]  = fmaf(_v0.x,(W),ACCV[0]);  ACCV[1]  = fmaf(_v0.y,(W),ACCV[1]); \
    ACCV[2]  = fmaf(_v0.z,(W),ACCV[2]);  ACCV[3]  = fmaf(_v0.w,(W),ACCV[3]); \
    ACCV[4]  = fmaf(_v1.x,(W),ACCV[4]);  ACCV[5]  = fmaf(_v1.y,(W),ACCV[5]); \
    ACCV[6]  = fmaf(_v1.z,(W),ACCV[6]);  ACCV[7]  = fmaf(_v1.w,(W),ACCV[7]); \
    ACCV[8]  = fmaf(_v2.x,(W),ACCV[8]);  ACCV[9]  = fmaf(_v2.y,(W),ACCV[9]); \
    ACCV[10] = fmaf(_v2.z,(W),ACCV[10]); ACCV[11] = fmaf(_v2.w,(W),ACCV[11]); \
    ACCV[12] = fmaf(_v3.x,(W),ACCV[12]); ACCV[13] = fmaf(_v3.y,(W),ACCV[13]); \
    ACCV[14] = fmaf(_v3.z,(W),ACCV[14]); ACCV[15] = fmaf(_v3.w,(W),ACCV[15]); \
} while (0)

#define MAC8(ACCV, BASE, W) do { \
    const float4* _p4 = (const float4*)(BASE); \
    float4 _v0 = _p4[0], _v1 = _p4[1]; \
    ACCV[0] = fmaf(_v0.x,(W),ACCV[0]); ACCV[1] = fmaf(_v0.y,(W),ACCV[1]); \
    ACCV[2] = fmaf(_v0.z,(W),ACCV[2]); ACCV[3] = fmaf(_v0.w,(W),ACCV[3]); \
    ACCV[4] = fmaf(_v1.x,(W),ACCV[4]); ACCV[5] = fmaf(_v1.y,(W),ACCV[5]); \
    ACCV[6] = fmaf(_v1.z,(W),ACCV[6]); ACCV[7] = fmaf(_v1.w,(W),ACCV[7]); \
} while (0)

#define MAC8_2(A1, A2, BASE, W1, W2) do { \
    const float4* _p4 = (const float4*)(BASE); \
    float4 _v0 = _p4[0], _v1 = _p4[1]; \
    A1[0] = fmaf(_v0.x,(W1),A1[0]); A2[0] = fmaf(_v0.x,(W2),A2[0]); \
    A1[1] = fmaf(_v0.y,(W1),A1[1]); A2[1] = fmaf(_v0.y,(W2),A2[1]); \
    A1[2] = fmaf(_v0.z,(W1),A1[2]); A2[2] = fmaf(_v0.z,(W2),A2[2]); \
    A1[3] = fmaf(_v0.w,(W1),A1[3]); A2[3] = fmaf(_v0.w,(W2),A2[3]); \
    A1[4] = fmaf(_v1.x,(W1),A1[4]); A2[4] = fmaf(_v1.x,(W2),A2[4]); \
    A1[5] = fmaf(_v1.y,(W1),A1[5]); A2[5] = fmaf(_v1.y,(W2),A2[5]); \
    A1[6] = fmaf(_v1.z,(W1),A1[6]); A2[6] = fmaf(_v1.z,(W2),A2[6]); \
    A1[7] = fmaf(_v1.w,(W1),A1[7]); A2[7] = fmaf(_v1.w,(W2),A2[7]); \
} while (0)

// ---------- build B matrices (bf16 hi/lo 3-term layout) from f32 weights ----------
__global__ __launch_bounds__(256) void k_prep_b(
    const float* __restrict__ w0, const float* __restrict__ gw0,
    const float* __restrict__ w12, const float* __restrict__ gw12,
    unsigned short* __restrict__ b0t, unsigned short* __restrict__ b1t,
    unsigned short* __restrict__ b2t)
{
    const int n = blockIdx.x;
    const int gate = n >> 7, oo = n & 127;
    const float sgn = (gate == 1) ? -0.5f : 1.0f;
    for (int k = threadIdx.x; k < 1056; k += 256) {
        float w; int isLo;
        if (k < 672) {
            int blk = k / 224, col = k - blk * 224;
            w = (col < 200) ? w0[(size_t)(128 + col) * 512 + n] : 0.f;
            isLo = (blk == 1);
        } else {
            int kg = k - 672, blkg = kg >> 7, colg = kg & 127;
            w = sgn * gw0[(size_t)(gate * 128 + colg) * 128 + oo];
            isLo = (blkg == 1);
        }
        unsigned short hi = f2bf(w);
        b0t[(size_t)n * 1056 + k] = isLo ? f2bf(w - bf2f(hi)) : hi;
    }
    for (int l = 0; l < 2; ++l) {
        unsigned short* dst = l ? b2t : b1t;
        for (int k = threadIdx.x; k < 768; k += 256) {
            float w; int isLo;
            if (k < 384) {
                int blk = k >> 7, col = k & 127;
                w = w12[(size_t)(l * 256 + 128 + col) * 512 + n];
                isLo = (blk == 1);
            } else {
                int kg = k - 384, blkg = kg >> 7, colg = kg & 127;
                w = sgn * gw12[(size_t)((l * 4 + gate) * 128 + colg) * 128 + oo];
                isLo = (blkg == 1);
            }
            unsigned short hi = f2bf(w);
            dst[(size_t)n * 768 + k] = isLo ? f2bf(w - bf2f(hi)) : hi;
        }
    }
}

// ---------- build Wh^T (bf16 hi|lo) for MFMA scan: wht[l][n][0:128]=hi, [128:256]=lo ----------
__global__ __launch_bounds__(128) void k_prep_wh(
    const float* __restrict__ w0, const float* __restrict__ w12,
    unsigned short* __restrict__ wht)
{
    const int n = blockIdx.x, l = blockIdx.y;
    const int k = threadIdx.x;   // 0..127
    const float* src = (l == 0) ? w0 : (w12 + (size_t)(l - 1) * 256 * 512);
    float w = src[(size_t)k * 512 + n];
    unsigned short hi = f2bf(w);
    wht[((size_t)l * 512 + n) * 256 + k] = hi;
    wht[((size_t)l * 512 + n) * 256 + 128 + k] = f2bf(w - bf2f(hi));
}

// ---------- one-time fusion-weight folding ----------
__global__ __launch_bounds__(128) void k_prep_fuse(
    const float* __restrict__ w_q, const float* __restrict__ b_q,
    const float* __restrict__ w_k, const float* __restrict__ b_k,
    const float* __restrict__ w_v, const float* __restrict__ b_v,
    const float* __restrict__ w_o,
    float* __restrict__ GT, float* __restrict__ WVO,
    float* __restrict__ e1, float* __restrict__ e2,
    float* __restrict__ e0, float* __restrict__ bvo)
{
    __shared__ float sk[128], sv[128];
    __shared__ float rtmp[8];
    const int i = blockIdx.x, f = threadIdx.x;
    sk[f] = w_k[(size_t)i * 128 + f];
    sv[f] = w_v[(size_t)i * 128 + f];
    __syncthreads();
    float g = 0.f, wv = 0.f;
    #pragma unroll 4
    for (int a = 0; a < 128; ++a) {
        g  = fmaf(w_q[(size_t)f * 128 + a], sk[a], g);
        wv = fmaf(sv[a], w_o[(size_t)a * 128 + f], wv);
    }
    GT[(size_t)i * 128 + f] = g;
    WVO[(size_t)i * 128 + f] = wv;
    float p1 = w_q[(size_t)i * 128 + f] * b_k[f];
    float p2 = sk[f] * b_q[f];
    #pragma unroll
    for (int sh = 32; sh > 0; sh >>= 1) {
        p1 += __shfl_xor(p1, sh, 64);
        p2 += __shfl_xor(p2, sh, 64);
    }
    if ((f & 63) == 0) { rtmp[(f >> 6) * 2] = p1; rtmp[(f >> 6) * 2 + 1] = p2; }
    __syncthreads();
    if (f == 0) { e1[i] = rtmp[0] + rtmp[2]; e2[i] = rtmp[1] + rtmp[3]; }
    if (i == 0) {
        float bw = 0.f;
        #pragma unroll 4
        for (int a = 0; a < 128; ++a) bw = fmaf(b_v[a], w_o[(size_t)a * 128 + f], bw);
        bvo[f] = bw;
        float p0 = b_q[f] * b_k[f];
        #pragma unroll
        for (int sh = 32; sh > 0; sh >>= 1) p0 += __shfl_xor(p0, sh, 64);
        if ((f & 63) == 0) rtmp[4 + (f >> 6)] = p0;
        __syncthreads();
        if (f == 0) e0[0] = rtmp[4] + rtmp[5];
    }
}

// ---------- folded TwoStageFusion, 256 threads (2 token-halves x 128 f) ----------
__global__ __launch_bounds__(256, 4) void k_gamma2(
    const float* __restrict__ ac, const float* __restrict__ pc,
    const float* __restrict__ rd,
    const float* __restrict__ w_amp, const float* __restrict__ b_amp,
    const float* __restrict__ w_ph,  const float* __restrict__ b_ph,
    const float* __restrict__ w_g,   const float* __restrict__ b_g,
    const float* __restrict__ w_r1,  const float* __restrict__ b_r1,
    const float* __restrict__ w_r2,  const float* __restrict__ b_r2,
    const float* __restrict__ GT,    const float* __restrict__ WVO,
    const float* __restrict__ e1,    const float* __restrict__ e2,
    const float* __restrict__ e0,    const float* __restrict__ bvo,
    const float* __restrict__ b_o,
    unsigned short* __restrict__ gsh, int segLen, int lgSeg, int tbase)
{
    __shared__ alignas(16) float catT[256][GPAD];
    __shared__ alignas(16) float rlT[128][GPAD];
    __shared__ float scin[4][16];
    __shared__ float red[2][2][8];

    const int tid = threadIdx.x;
    const int f = tid & 127;
    const int th = tid >> 7;        // token half
    const int t0 = th * 8;
    const int r0 = blockIdx.x * 16;
    const int b = r0 >> lgSeg;
    const int tl = r0 & (segLen - 1);
    const int tau0 = tbase + tl - 1;

    if (tid < 64) {
        int j = tid >> 4, tt = tid & 15;
        int tau = tau0 + tt; if (tau < 0) tau = 0;
        size_t tok = (size_t)b * TT + tau;
        float v;
        if (j == 0) v = ac[tok];
        else if (j == 1) v = pc[tok];
        else v = rd[tok * 2 + (j - 2)];
        scin[j][tt] = v;
    }
    const float wa = w_amp[f], ba = b_amp[f];
    const float wp = w_ph[f],  bpv = b_ph[f];
    const float w1a = w_r1[f], w1b = w_r1[128 + f];
    const float br1 = b_r1[f], br2v = b_r2[f];
    const float bg = b_g[f];
    __syncthreads();

    float ph8[8], am8[8];
    #pragma unroll
    for (int t = 0; t < 8; ++t) {
        float a = scin[0][t0 + t], p = scin[1][t0 + t];
        float r0v = scin[2][t0 + t], r1v = scin[3][t0 + t];
        float phv = tanh_(fmaf(p, wp, bpv));
        float amv = tanh_(fmaf(a, wa, ba));
        ph8[t] = phv; am8[t] = amv;
        catT[f][t0 + t] = phv;
        catT[128 + f][t0 + t] = amv;
        rlT[f][t0 + t] = tanh_(fmaf(r1v, w1b, fmaf(r0v, w1a, br1)));
    }
    __syncthreads();

    // pass 1: gate logits (K=256) + rlos layer2 (K=128)
    float bacc[8], racc[8];
    #pragma unroll
    for (int t = 0; t < 8; ++t) { bacc[t] = 0.f; racc[t] = 0.f; }
    #pragma unroll 2
    for (int i = 0; i < 128; ++i) {
        float wg1 = w_g[i * 128 + f];
        float wg2 = w_g[(128 + i) * 128 + f];
        float wr  = w_r2[i * 128 + f];
        MAC8(bacc, &catT[i][t0], wg1);
        MAC8(bacc, &catT[128 + i][t0], wg2);
        MAC8(racc, &rlT[i][t0], wr);
    }
    float corr8[8], rl8[8];
    #pragma unroll
    for (int t = 0; t < 8; ++t) {
        float beta = sigm(bacc[t] + bg);
        corr8[t] = fmaf(beta, ph8[t] - am8[t], am8[t]);
        rl8[t] = tanh_(racc[t] + br2v);
    }
    __syncthreads();
    #pragma unroll
    for (int t = 0; t < 8; ++t) rlT[f][t0 + t] = rl8[t];
    __syncthreads();

    // pass 2 (dual): u = G.rl  and  vo = rl.(WvWo)
    float uacc[8], voacc[8];
    #pragma unroll
    for (int t = 0; t < 8; ++t) { uacc[t] = 0.f; voacc[t] = 0.f; }
    #pragma unroll 2
    for (int i = 0; i < 128; ++i) {
        float wu = GT[i * 128 + f];
        float wv = WVO[i * 128 + f];
        MAC8_2(uacc, voacc, &rlT[i][t0], wu, wv);
    }

    const int lane = tid & 63, wv2 = (tid >> 6) & 1;
    const float e1f = e1[f], e2f = e2[f], e0v = e0[0];
    #pragma unroll
    for (int t = 0; t < 8; ++t) {
        float pdot = fmaf(corr8[t], uacc[t] + e1f, rl8[t] * e2f);
        #pragma unroll
        for (int sh = 32; sh > 0; sh >>= 1) pdot += __shfl_xor(pdot, sh, 64);
        if (lane == 0) red[th][wv2][t] = pdot;
    }
    __syncthreads();
    const float bvof = bvo[f], bof = b_o[f];
    #pragma unroll
    for (int t = 0; t < 8; ++t) {
        float attn = sigm((red[th][0][t] + red[th][1][t] + e0v) * 0.088388347648318447f);
        float g = fmaf(attn, voacc[t] + bvof, bof);
        if (tau0 + t0 + t < 0) g = 0.f;
        unsigned short hi = f2bf(g);
        gsh[(size_t)(r0 + t0 + t) * 256 + f] = hi;
        gsh[(size_t)(r0 + t0 + t) * 256 + 128 + f] = f2bf(g - bf2f(hi));
    }
}

// ---------- legacy (un-folded) fusion kernel: fallback if workspace is tight ----------
__global__ __launch_bounds__(128) void k_gamma(
    const float* __restrict__ ac, const float* __restrict__ pc,
    const float* __restrict__ rd,
    const float* __restrict__ w_amp, const float* __restrict__ b_amp,
    const float* __restrict__ w_ph,  const float* __restrict__ b_ph,
    const float* __restrict__ w_g,   const float* __restrict__ b_g,
    const float* __restrict__ w_r1,  const float* __restrict__ b_r1,
    const float* __restrict__ w_r2,  const float* __restrict__ b_r2,
    const float* __restrict__ w_q,   const float* __restrict__ b_q,
    const float* __restrict__ w_k,   const float* __restrict__ b_k,
    const float* __restrict__ w_v,   const float* __restrict__ b_v,
    const float* __restrict__ w_o,   const float* __restrict__ b_o,
    unsigned short* __restrict__ gsh, int segLen, int lgSeg, int tbase)
{
    __shared__ alignas(16) float catT[256][GPAD];
    __shared__ alignas(16) float rlT[128][GPAD];
    __shared__ alignas(16) float avT[128][GPAD];
    __shared__ float scin[4][16];
    __shared__ float red[2][16];

    const int f = threadIdx.x;
    const int r0 = blockIdx.x * 16;
    const int b = r0 >> lgSeg;
    const int tl = r0 & (segLen - 1);
    const int tau0 = tbase + tl - 1;

    if (f < 64) {
        int j = f >> 4, tt = f & 15;
        int tau = tau0 + tt; if (tau < 0) tau = 0;
        size_t tok = (size_t)b * TT + tau;
        float v;
        if (j == 0) v = ac[tok];
        else if (j == 1) v = pc[tok];
        else v = rd[tok * 2 + (j - 2)];
        scin[j][tt] = v;
    }
    const float wa = w_amp[f], ba = b_amp[f];
    const float wp = w_ph[f],  bpv = b_ph[f];
    const float w1a = w_r1[f], w1b = w_r1[128 + f];
    const float br1 = b_r1[f], br2 = b_r2[f];
    const float bg = b_g[f];
    const float bqv = b_q[f], bkv = b_k[f];
    const float bvv = b_v[f], bov = b_o[f];
    __syncthreads();

    float ph16[16], am16[16];
    #pragma unroll
    for (int t = 0; t < 16; ++t) {
        float a = scin[0][t], p = scin[1][t], r0v = scin[2][t], r1v = scin[3][t];
        float phv = tanh_(fmaf(p, wp, bpv));
        float amv = tanh_(fmaf(a, wa, ba));
        ph16[t] = phv; am16[t] = amv;
        catT[f][t] = phv;
        catT[128 + f][t] = amv;
        rlT[f][t] = tanh_(fmaf(r1v, w1b, fmaf(r0v, w1a, br1)));
    }
    __syncthreads();

    float bacc[16], racc[16];
    #pragma unroll
    for (int t = 0; t < 16; ++t) { bacc[t] = 0.f; racc[t] = 0.f; }
    #pragma unroll 2
    for (int i = 0; i < 128; ++i) {
        float wg1 = w_g[i * 128 + f];
        float wg2 = w_g[(128 + i) * 128 + f];
        float wr  = w_r2[i * 128 + f];
        MAC16(bacc, &catT[i][0], wg1);
        MAC16(bacc, &catT[128 + i][0], wg2);
        MAC16(racc, &rlT[i][0], wr);
    }
    float corr16[16], rl16[16];
    #pragma unroll
    for (int t = 0; t < 16; ++t) {
        float beta = sigm(bacc[t] + bg);
        corr16[t] = fmaf(beta, ph16[t] - am16[t], am16[t]);
        rl16[t] = tanh_(racc[t] + br2);
    }
    __syncthreads();
    #pragma unroll
    for (int t = 0; t < 16; ++t) { catT[f][t] = corr16[t]; rlT[f][t] = rl16[t]; }
    __syncthreads();

    float qa[16], ka[16], va[16];
    #pragma unroll
    for (int t = 0; t < 16; ++t) { qa[t] = 0.f; ka[t] = 0.f; va[t] = 0.f; }
    #pragma unroll 2
    for (int i = 0; i < 128; ++i) {
        float wq = w_q[i * 128 + f];
        float wk = w_k[i * 128 + f];
        float wv = w_v[i * 128 + f];
        MAC16(qa, &catT[i][0], wq);
        MAC16(ka, &rlT[i][0], wk);
        MAC16(va, &rlT[i][0], wv);
    }
    const int lane = f & 63, wvi = f >> 6;
    #pragma unroll
    for (int t = 0; t < 16; ++t) {
        float pdot = (qa[t] + bqv) * (ka[t] + bkv);
        #pragma unroll
        for (int sh = 32; sh > 0; sh >>= 1) pdot += __shfl_xor(pdot, sh, 64);
        if (lane == 0) red[wvi][t] = pdot;
    }
    __syncthreads();
    #pragma unroll
    for (int t = 0; t < 16; ++t) {
        float attn = sigm((red[0][t] + red[1][t]) * 0.088388347648318447f);
        avT[f][t] = attn * (va[t] + bvv);
    }
    __syncthreads();
    float oacc[16];
    #pragma unroll
    for (int t = 0; t < 16; ++t) oacc[t] = 0.f;
    #pragma unroll 2
    for (int i = 0; i < 128; ++i) {
        float wo = w_o[i * 128 + f];
        MAC16(oacc, &avT[i][0], wo);
    }
    #pragma unroll
    for (int t = 0; t < 16; ++t) {
        float g = oacc[t] + bov;
        if (tau0 + t < 0) g = 0.f;
        unsigned short hi = f2bf(g);
        gsh[(size_t)(r0 + t) * 256 + f] = hi;
        gsh[(size_t)(r0 + t) * 256 + 128 + f] = f2bf(g - bf2f(hi));
    }
}

// ---------- stage |hrrp| into bf16 hi/lo ----------
__global__ __launch_bounds__(256) void k_stagex(
    const float* __restrict__ hrrp, unsigned short* __restrict__ xs,
    int segLen, int lgSeg, int tbase)
{
    const int m = blockIdx.x;
    const int b = m >> lgSeg, tl = m & (segLen - 1);
    const size_t bt = (size_t)b * TT + tbase + tl;
    const int col = threadIdx.x;
    if (col < 224) {
        float v = (col < 200) ? fabsf(hrrp[bt * DD + col]) : 0.f;
        unsigned short hi = f2bf(v);
        xs[(size_t)m * 448 + col] = hi;
        xs[(size_t)m * 448 + 224 + col] = f2bf(v - bf2f(hi));
    }
}

// ---------- A-fragment address for 3-term layout ----------
template<int KTOT>
__device__ __forceinline__ const unsigned short* addrA(
    const unsigned short* __restrict__ Ax, const unsigned short* __restrict__ Ag,
    int m, int ko)
{
    if (KTOT == 1056) {
        if (ko < 672) {
            int blk = ko / 224, col = ko - blk * 224;
            return Ax + (size_t)m * 448 + (blk == 2 ? 224 : 0) + col;
        }
        int kg = ko - 672, blkg = kg >> 7, colg = kg & 127;
        return Ag + (size_t)m * 256 + (blkg == 2 ? 128 : 0) + colg;
    } else {
        if (ko < 384) {
            int blk = ko >> 7, col = ko & 127;
            return Ax + (size_t)m * 256 + (blk == 2 ? 128 : 0) + col;
        }
        int kg = ko - 384, blkg = kg >> 7, colg = kg & 127;
        return Ag + (size_t)m * 256 + (blkg == 2 ? 128 : 0) + colg;
    }
}

// ---------- bf16 MFMA GEMM (+bias[n]), global_load_lds double-buffered ----------
template<int KTOT>
__global__ __launch_bounds__(256) void k_gemm(
    const unsigned short* __restrict__ Ax, const unsigned short* __restrict__ Ag,
    const unsigned short* __restrict__ Bt, const float* __restrict__ bp,
    float* __restrict__ C)
{
    __shared__ alignas(16) unsigned short Als[2][4096];
    __shared__ alignas(16) unsigned short Bls[2][4096];
    const int tid = threadIdx.x;
    const int m0 = blockIdx.x * 128, n0 = blockIdx.y * 128;
    const int wave = tid >> 6, lane = tid & 63;
    const int lm = lane & 15, lq = lane >> 4;
    const int wm = wave >> 1, wn = wave & 1;
    const int srow = tid >> 2, scol = (tid & 3) * 8;
    const int wb = wave * 512;

    const f32x4 vzero = {0.f, 0.f, 0.f, 0.f};
    f32x4 acc[4][4];
    #pragma unroll
    for (int x = 0; x < 4; ++x)
        #pragma unroll
        for (int y = 0; y < 4; ++y) acc[x][y] = vzero;

    float bn[4];
    #pragma unroll
    for (int nt = 0; nt < 4; ++nt) bn[nt] = bp[n0 + wn * 64 + nt * 16 + lm];

    constexpr int NKB = KTOT / 32;

    #define STAGE(buf, kb) do { \
        const int _ko = (kb) * 32 + scol; \
        gll16(addrA<KTOT>(Ax, Ag, m0 + srow, _ko),        &Als[buf][wb]); \
        gll16(addrA<KTOT>(Ax, Ag, m0 + 64 + srow, _ko),   &Als[buf][2048 + wb]); \
        gll16(Bt + (size_t)(n0 + srow) * KTOT + _ko,      &Bls[buf][wb]); \
        gll16(Bt + (size_t)(n0 + 64 + srow) * KTOT + _ko, &Bls[buf][2048 + wb]); \
    } while (0)

    STAGE(0, 0);
    __syncthreads();
    int cur = 0;
    for (int kb = 0; kb < NKB; ++kb) {
        if (kb + 1 < NKB) STAGE(cur ^ 1, kb + 1);
        bf16x8 af[4], bfr[4];
        #pragma unroll
        for (int mt = 0; mt < 4; ++mt)
            af[mt] = *(const bf16x8*)&Als[cur][(wm * 64 + mt * 16 + lm) * 32 + lq * 8];
        #pragma unroll
        for (int nt = 0; nt < 4; ++nt)
            bfr[nt] = *(const bf16x8*)&Bls[cur][(wn * 64 + nt * 16 + lm) * 32 + lq * 8];
        #pragma unroll
        for (int mt = 0; mt < 4; ++mt)
            #pragma unroll
            for (int nt = 0; nt < 4; ++nt)
                acc[mt][nt] = __builtin_amdgcn_mfma_f32_16x16x32_bf16(af[mt], bfr[nt], acc[mt][nt], 0, 0, 0);
        __syncthreads();
        cur ^= 1;
    }
    #undef STAGE

    #pragma unroll
    for (int mt = 0; mt < 4; ++mt) {
        #pragma unroll
        for (int nt = 0; nt < 4; ++nt) {
            const int m = m0 + wm * 64 + mt * 16 + lq * 4;
            const int n = n0 + wn * 64 + nt * 16 + lm;
            #pragma unroll
            for (int r = 0; r < 4; ++r)
                C[(size_t)(m + r) * 512 + n] = acc[mt][nt][r] + bn[nt];
        }
    }
}

// ---------- MFMA recurrent scan: 16 batches/block, 16 blocks ----------
// pre already contains bias (added by k_gemm). wt = Wh^T [512][256] bf16 hi|lo.
template<int STORE_XH, int FINAL>
__global__ __launch_bounds__(512, 2) void k_scan_m(
    const float* __restrict__ pre, const unsigned short* __restrict__ wt,
    float* __restrict__ st_h, float* __restrict__ st_c,
    unsigned short* __restrict__ xh, float* __restrict__ outp,
    const float* __restrict__ regw, const float* __restrict__ regb,
    int first, int R)
{
    __shared__ alignas(16) float zb[16 * 516];          // [m][n] padded
    __shared__ alignas(16) unsigned short Hh[16 * 136]; // h hi, row stride 272B
    __shared__ alignas(16) unsigned short Hl[16 * 136]; // h lo

    const int tid = threadIdx.x;
    const int wave = tid >> 6, lane = tid & 63;
    const int lm = lane & 15, lq = lane >> 4;
    const int bk = blockIdx.x;

    // persistent W fragments: wave owns n-cols [wave*64, wave*64+64)
    bf16x8 wh[4][4], wl[4][4];
    #pragma unroll
    for (int nt = 0; nt < 4; ++nt) {
        const unsigned short* wr = wt + (size_t)(wave * 64 + nt * 16 + lm) * 256 + lq * 8;
        #pragma unroll
        for (int kb = 0; kb < 4; ++kb) {
            wh[nt][kb] = *(const bf16x8*)(wr + kb * 32);
            wl[nt][kb] = *(const bf16x8*)(wr + 128 + kb * 32);
        }
    }

    // gate mapping: thread -> (mg, og), owns o = og+32j, j=0..3
    const int mg = tid >> 5, og = tid & 31;
    const size_t bglob = (size_t)bk * 16 + mg;
    float c[4], hcur[4];
    #pragma unroll
    for (int j = 0; j < 4; ++j) {
        float h0 = 0.f; c[j] = 0.f;
        if (!first) { h0 = st_h[bglob * 128 + og + 32 * j]; c[j] = st_c[bglob * 128 + og + 32 * j]; }
        hcur[j] = h0;
        unsigned short hi = f2bf(h0);
        Hh[mg * 136 + og + 32 * j] = hi;
        Hl[mg * 136 + og + 32 * j] = f2bf(h0 - bf2f(hi));
    }
    const float* prem = pre + (bglob * R) * 512;
    float pv[16], pn[16];
    #pragma unroll
    for (int g = 0; g < 4; ++g)
        #pragma unroll
        for (int j = 0; j < 4; ++j)
            pv[g * 4 + j] = prem[g * 128 + og + 32 * j];
    __syncthreads();

    for (int t = 0; t < R; ++t) {
        // A-frags from LDS (row stride 272B -> 2-way bank alias, free)
        bf16x8 ah[4], al[4];
        #pragma unroll
        for (int kb = 0; kb < 4; ++kb) {
            ah[kb] = *(const bf16x8*)&Hh[lm * 136 + kb * 32 + lq * 8];
            al[kb] = *(const bf16x8*)&Hl[lm * 136 + kb * 32 + lq * 8];
        }
        // prefetch next-step pre
        if (t + 1 < R) {
            const float* pnx = prem + (size_t)(t + 1) * 512;
            #pragma unroll
            for (int g = 0; g < 4; ++g)
                #pragma unroll
                for (int j = 0; j < 4; ++j)
                    pn[g * 4 + j] = pnx[g * 128 + og + 32 * j];
        }
        // Z = H @ Wh  (3-term: hhi*Whi + hhi*Wlo + hlo*Whi)
        #pragma unroll
        for (int nt = 0; nt < 4; ++nt) {
            f32x4 acc = {0.f, 0.f, 0.f, 0.f};
            #pragma unroll
            for (int kb = 0; kb < 4; ++kb)
                acc = __builtin_amdgcn_mfma_f32_16x16x32_bf16(ah[kb], wh[nt][kb], acc, 0, 0, 0);
            #pragma unroll
            for (int kb = 0; kb < 4; ++kb)
                acc = __builtin_amdgcn_mfma_f32_16x16x32_bf16(ah[kb], wl[nt][kb], acc, 0, 0, 0);
            #pragma unroll
            for (int kb = 0; kb < 4; ++kb)
                acc = __builtin_amdgcn_mfma_f32_16x16x32_bf16(al[kb], wh[nt][kb], acc, 0, 0, 0);
            const int n = wave * 64 + nt * 16 + lm;
            #pragma unroll
            for (int r = 0; r < 4; ++r)
                zb[(lq * 4 + r) * 516 + n] = acc[r];
        }
        __syncthreads();
        // gates
        #pragma unroll
        for (int j = 0; j < 4; ++j) {
            const int o = og + 32 * j;
            const float zi = zb[mg * 516 + o]        + pv[j];
            const float zf = zb[mg * 516 + 128 + o]  + pv[4 + j];
            const float zc = zb[mg * 516 + 256 + o]  + pv[8 + j];
            const float zo = zb[mg * 516 + 384 + o]  + pv[12 + j];
            const float ig = sigm(zi);
            const float fg = sigm(zf);
            const float ch = tanh_(zc);
            const float ogt = sigm(zo);
            c[j] = fg * c[j] + ig * ch;
            const float h2 = ogt * tanh_(c[j]);
            hcur[j] = h2;
            unsigned short hi = f2bf(h2);
            unsigned short lo = f2bf(h2 - bf2f(hi));
            Hh[mg * 136 + o] = hi;
            Hl[mg * 136 + o] = lo;
            if (STORE_XH) {
                size_t row = bglob * R + t;
                xh[row * 256 + o] = hi;
                xh[row * 256 + 128 + o] = lo;
            }
        }
        #pragma unroll
        for (int i = 0; i < 16; ++i) pv[i] = pn[i];
        __syncthreads();
    }
    // save state
    #pragma unroll
    for (int j = 0; j < 4; ++j) {
        st_h[bglob * 128 + og + 32 * j] = hcur[j];
        st_c[bglob * 128 + og + 32 * j] = c[j];
    }
    if (FINAL) {
        #pragma unroll
        for (int j = 0; j < 4; ++j) zb[mg * 516 + og + 32 * j] = hcur[j];
        __syncthreads();
        if (tid < 32) {
            const int m = tid >> 1, oo = tid & 1;
            float s = regb[oo];
            #pragma unroll 4
            for (int i = 0; i < 128; ++i) s = fmaf(zb[m * 516 + i], regw[i * 2 + oo], s);
            outp[((size_t)bk * 16 + m) * 2 + oo] = s;
        }
    }
}

// ---------- legacy recurrent scan (fallback; bias now comes in via pre) ----------
template<int STORE_XH, int FINAL>
__global__ __launch_bounds__(512, 2) void k_scan(
    const float* __restrict__ pre, const float* __restrict__ Wh,
    float* __restrict__ st_h, float* __restrict__ st_c,
    unsigned short* __restrict__ xh, float* __restrict__ outp,
    const float* __restrict__ regw, const float* __restrict__ regb,
    int first, int R)
{
    const int o = threadIdx.x;
    const int b = blockIdx.x;
    __shared__ alignas(16) float hbuf[128];
    __shared__ float zbuf[512];
    float wc[128];
    #pragma unroll
    for (int i = 0; i < 128; ++i) wc[i] = Wh[i * 512 + o];
    float c = 0.f;
    if (o < 128) {
        float h0 = 0.f;
        if (!first) { h0 = st_h[b * 128 + o]; c = st_c[b * 128 + o]; }
        hbuf[o] = h0;
    }
    __syncthreads();
    const float* preb = pre + (size_t)b * R * 512;
    float p = preb[o];
    for (int t = 0; t < R; ++t) {
        const float q = (t < R - 1) ? preb[(t + 1) * 512 + o] : 0.f;
        float acc_a = p, acc_b = 0.f;
        #pragma unroll
        for (int i8 = 0; i8 < 16; ++i8) {
            const float4 ha = *(const float4*)&hbuf[i8 * 8];
            const float4 hb = *(const float4*)&hbuf[i8 * 8 + 4];
            acc_a = fmaf(ha.x, wc[i8 * 8 + 0], acc_a);
            acc_b = fmaf(hb.x, wc[i8 * 8 + 4], acc_b);
            acc_a = fmaf(ha.y, wc[i8 * 8 + 1], acc_a);
            acc_b = fmaf(hb.y, wc[i8 * 8 + 5], acc_b);
            acc_a = fmaf(ha.z, wc[i8 * 8 + 2], acc_a);
            acc_b = fmaf(hb.z, wc[i8 * 8 + 6], acc_b);
            acc_a = fmaf(ha.w, wc[i8 * 8 + 3], acc_a);
            acc_b = fmaf(hb.w, wc[i8 * 8 + 7], acc_b);
        }
        zbuf[o] = acc_a + acc_b;
        __syncthreads();
        if (o < 128) {
            const float ig = sigm(zbuf[o]);
            const float fg = sigm(zbuf[o + 128]);
            const float ch = tanh_(zbuf[o + 256]);
            const float og = sigm(zbuf[o + 384]);
            c = fg * c + ig * ch;
            const float h2 = og * tanh_(c);
            hbuf[o] = h2;
            if (STORE_XH) {
                unsigned short hi = f2bf(h2);
                size_t row = (size_t)b * R + t;
                xh[row * 256 + o] = hi;
                xh[row * 256 + 128 + o] = f2bf(h2 - bf2f(hi));
            }
        }
        __syncthreads();
        p = q;
    }
    if (o < 128) { st_h[b * 128 + o] = hbuf[o]; st_c[b * 128 + o] = c; }
    if (FINAL && o < 2) {
        float s = regb[o];
        #pragma unroll 4
        for (int i = 0; i < 128; ++i) s = fmaf(hbuf[i], regw[i * 2 + o], s);
        outp[b * 2 + o] = s;
    }
}

// ---------- host ----------
extern "C" void kernel_launch(void* const* d_in, const int* in_sizes, int n_in,
                              void* d_out, int out_size, void* d_ws, size_t ws_size,
                              hipStream_t stream)
{
    const float* hrrp = (const float*)d_in[0];
    const float* ac   = (const float*)d_in[1];
    const float* pc   = (const float*)d_in[2];
    const float* rd   = (const float*)d_in[3];
    const float* w_amp= (const float*)d_in[4];
    const float* b_amp= (const float*)d_in[5];
    const float* w_ph = (const float*)d_in[6];
    const float* b_ph = (const float*)d_in[7];
    const float* w_g  = (const float*)d_in[8];
    const float* b_g  = (const float*)d_in[9];
    const float* w_r1 = (const float*)d_in[10];
    const float* b_r1 = (const float*)d_in[11];
    const float* w_r2 = (const float*)d_in[12];
    const float* b_r2 = (const float*)d_in[13];
    const float* w_q  = (const float*)d_in[14];
    const float* b_q  = (const float*)d_in[15];
    const float* w_k  = (const float*)d_in[16];
    const float* b_k  = (const float*)d_in[17];
    const float* w_v  = (const float*)d_in[18];
    const float* b_v  = (const float*)d_in[19];
    const float* w_o  = (const float*)d_in[20];
    const float* b_o  = (const float*)d_in[21];
    const float* w0   = (const float*)d_in[22];
    const float* b0   = (const float*)d_in[23];
    const float* gw0  = (const float*)d_in[24];
    const float* w12  = (const float*)d_in[25];
    const float* b12  = (const float*)d_in[26];
    const float* gw12 = (const float*)d_in[27];
    const float* regw = (const float*)d_in[28];
    const float* regb = (const float*)d_in[29];
    float* outp = (float*)d_out;

    const size_t need64 = 68452352ULL, need32 = 35946496ULL;
    const size_t EXTRA = 132864ULL;     // GT + WVO + e1 + e2 + bvo + e0
    const size_t WHX   = 786432ULL;     // wht[3][512][256] bf16
    int R, lg, folded, mscan;
    if      (ws_size >= need64 + EXTRA + WHX) { R = 64; lg = 6; folded = 1; mscan = 1; }
    else if (ws_size >= need64 + EXTRA)       { R = 64; lg = 6; folded = 1; mscan = 0; }
    else if (ws_size >= need64)               { R = 64; lg = 6; folded = 0; mscan = 0; }
    else if (ws_size >= need32 + EXTRA + WHX) { R = 32; lg = 5; folded = 1; mscan = 1; }
    else if (ws_size >= need32 + EXTRA)       { R = 32; lg = 5; folded = 1; mscan = 0; }
    else if (ws_size >= need32)               { R = 32; lg = 5; folded = 0; mscan = 0; }
    else return;
    const int NSEG = TT / R;
    const int MR = BB * R;

    char* ws = (char*)d_ws;
    size_t off = 0;
    float* pre = (float*)(ws + off);                   off += (size_t)MR * 512 * 4;
    unsigned short* gsh = (unsigned short*)(ws + off); off += (size_t)MR * 256 * 2;
    unsigned short* xh  = (unsigned short*)(ws + off); off += (size_t)MR * 256 * 2;
    unsigned short* xs  = (unsigned short*)(ws + off); off += (size_t)MR * 448 * 2;
    float* sh0 = (float*)(ws + off); off += 131072;
    float* sc0 = (float*)(ws + off); off += 131072;
    float* sh1 = (float*)(ws + off); off += 131072;
    float* sc1 = (float*)(ws + off); off += 131072;
    float* sh2 = (float*)(ws + off); off += 131072;
    float* sc2 = (float*)(ws + off); off += 131072;
    unsigned short* b0t = (unsigned short*)(ws + off); off += 512 * 1056 * 2;
    unsigned short* b1t = (unsigned short*)(ws + off); off += 512 * 768 * 2;
    unsigned short* b2t = (unsigned short*)(ws + off); off += 512 * 768 * 2;
    float* GT = nullptr; float* WVO = nullptr;
    float* e1p = nullptr; float* e2p = nullptr; float* bvop = nullptr; float* e0p = nullptr;
    unsigned short* wht = nullptr;
    if (folded) {
        GT   = (float*)(ws + off); off += 128 * 128 * 4;
        WVO  = (float*)(ws + off); off += 128 * 128 * 4;
        e1p  = (float*)(ws + off); off += 512;
        e2p  = (float*)(ws + off); off += 512;
        bvop = (float*)(ws + off); off += 512;
        e0p  = (float*)(ws + off); off += 256;
    }
    if (mscan) { wht = (unsigned short*)(ws + off); off += WHX; }

    k_prep_b<<<512, 256, 0, stream>>>(w0, gw0, w12, gw12, b0t, b1t, b2t);
    if (folded)
        k_prep_fuse<<<128, 128, 0, stream>>>(w_q, b_q, w_k, b_k, w_v, b_v, w_o,
                                             GT, WVO, e1p, e2p, e0p, bvop);
    if (mscan)
        k_prep_wh<<<dim3(512, 3), 128, 0, stream>>>(w0, w12, wht);

    for (int seg = 0; seg < NSEG; ++seg) {
        const int first = (seg == 0) ? 1 : 0;
        const int tbase = seg * R;
        if (folded)
            k_gamma2<<<MR / 16, 256, 0, stream>>>(ac, pc, rd, w_amp, b_amp, w_ph, b_ph,
                                                  w_g, b_g, w_r1, b_r1, w_r2, b_r2,
                                                  GT, WVO, e1p, e2p, e0p, bvop, b_o,
                                                  gsh, R, lg, tbase);
        else
            k_gamma<<<MR / 16, 128, 0, stream>>>(ac, pc, rd, w_amp, b_amp, w_ph, b_ph,
                                                 w_g, b_g, w_r1, b_r1, w_r2, b_r2,
                                                 w_q, b_q, w_k, b_k, w_v, b_v, w_o, b_o,
                                                 gsh, R, lg, tbase);
        k_stagex<<<MR, 256, 0, stream>>>(hrrp, xs, R, lg, tbase);
        // layer 0
        k_gemm<1056><<<dim3(MR / 128, 4), 256, 0, stream>>>(xs, gsh, b0t, b0, pre);
        if (mscan)
            k_scan_m<1, 0><<<16, 512, 0, stream>>>(pre, wht, sh0, sc0, xh,
                                                   nullptr, nullptr, nullptr, first, R);
        else
            k_scan<1, 0><<<BB, 512, 0, stream>>>(pre, w0, sh0, sc0, xh,
                                                 nullptr, nullptr, nullptr, first, R);
        // layer 1
        k_gemm<768><<<dim3(MR / 128, 4), 256, 0, stream>>>(xh, gsh, b1t, b12, pre);
        if (mscan)
            k_scan_m<1, 0><<<16, 512, 0, stream>>>(pre, wht + 512 * 256, sh1, sc1, xh,
                                                   nullptr, nullptr, nullptr, first, R);
        else
            k_scan<1, 0><<<BB, 512, 0, stream>>>(pre, w12, sh1, sc1, xh,
                                                 nullptr, nullptr, nullptr, first, R);
        // layer 2
        k_gemm<768><<<dim3(MR / 128, 4), 256, 0, stream>>>(xh, gsh, b2t, b12 + 512, pre);
        if (seg < NSEG - 1) {
            if (mscan)
                k_scan_m<0, 0><<<16, 512, 0, stream>>>(pre, wht + 2 * 512 * 256, sh2, sc2,
                                                       nullptr, nullptr, nullptr, nullptr, first, R);
            else
                k_scan<0, 0><<<BB, 512, 0, stream>>>(pre, w12 + 256 * 512, sh2, sc2,
                                                     nullptr, nullptr, nullptr, nullptr, first, R);
        } else {
            if (mscan)
                k_scan_m<0, 1><<<16, 512, 0, stream>>>(pre, wht + 2 * 512 * 256, sh2, sc2,
                                                       nullptr, outp, regw, regb, first, R);
            else
                k_scan<0, 1><<<BB, 512, 0, stream>>>(pre, w12 + 256 * 512, sh2, sc2,
                                                     nullptr, outp, regw, regb, first, R);
        }
    }
}

// Round 4
// 3176.748 us; speedup vs baseline: 1.7292x; 1.7292x over previous
//
#include <hip/hip_runtime.h>

#define BB 256
#define TT 512
#define DD 200

// ---------- helpers ----------
__device__ __forceinline__ float bf2f(unsigned short u) {
    return __uint_as_float(((unsigned int)u) << 16);
}
__device__ __forceinline__ unsigned short f2bf(float f) {
    unsigned int u = __float_as_uint(f);
    u += 0x7FFFu + ((u >> 16) & 1u);
    return (unsigned short)(u >> 16);
}
__device__ __forceinline__ float sigm(float x) { return 1.0f / (1.0f + __expf(-x)); }
__device__ __forceinline__ float tanh_(float x) { return 1.0f - 2.0f / (__expf(2.0f * x) + 1.0f); }

typedef __bf16 bf16x8 __attribute__((ext_vector_type(8)));
typedef float  f32x4  __attribute__((ext_vector_type(4)));

#define GPAD 20

// async global->LDS 16B (dest = wave-uniform base + lane*16)
__device__ __forceinline__ void gll16(const unsigned short* g, unsigned short* l) {
    __builtin_amdgcn_global_load_lds(
        (const __attribute__((address_space(1))) unsigned int*)g,
        (__attribute__((address_space(3))) unsigned int*)l,
        16, 0, 0);
}

#define MAC16(ACCV, BASE, W) do { \
    const float4* _p4 = (const float4*)(BASE); \
    float4 _v0 = _p4[0], _v1 = _p4[1], _v2 = _p4[2], _v3 = _p4[3]; \
    ACCV[0]  = fmaf(_v0.x,(W),ACCV[0]);  ACCV[1]  = fmaf(_v0.y,(W),ACCV[1]); \
    ACCV[2]  = fmaf(_v0.z,(W),ACCV[2]);  ACCV[3]  = fmaf(_v0.w,(W),ACCV[3]); \
    ACCV[4]  = fmaf(_v1.x,(W),ACCV[4]);  ACCV[5]  = fmaf(_v1.y,(W),ACCV[5]); \
    ACCV[6]  = fmaf(_v1.z,(W),ACCV[6]);  ACCV[7]  = fmaf(_v1.w,(W),ACCV[7]); \
    ACCV[8]  = fmaf(_v2.x,(W),ACCV[8]);  ACCV[9]  = fmaf(_v2.y,(W),ACCV[9]); \
    ACCV[10] = fmaf(_v2.z,(W),ACCV[10]); ACCV[11] = fmaf(_v2.w,(W),ACCV[11]); \
    ACCV[12] = fmaf(_v3.x,(W),ACCV[12]); ACCV[13] = fmaf(_v3.y,(W),ACCV[13]); \
    ACCV[14] = fmaf(_v3.z,(W),ACCV[14]); ACCV[15] = fmaf(_v3.w,(W),ACCV[15]); \
} while (0)

#define MAC8(ACCV, BASE, W) do { \
    const float4* _p4 = (const float4*)(BASE); \
    float4 _v0 = _p4[0], _v1 = _p4[1]; \
    ACCV[0] = fmaf(_v0.x,(W),ACCV[0]); ACCV[1] = fmaf(_v0.y,(W),ACCV[1]); \
    ACCV[2] = fmaf(_v0.z,(W),ACCV[2]); ACCV[3] = fmaf(_v0.w,(W),ACCV[3]); \
    ACCV[4] = fmaf(_v1.x,(W),ACCV[4]); ACCV[5] = fmaf(_v1.y,(W),ACCV[5]); \
    ACCV[6] = fmaf(_v1.z,(W),ACCV[6]); ACCV[7] = fmaf(_v1.w,(W),ACCV[7]); \
} while (0)

#define MAC8_2(A1, A2, BASE, W1, W2) do { \
    const float4* _p4 = (const float4*)(BASE); \
    float4 _v0 = _p4[0], _v1 = _p4[1]; \
    A1[0] = fmaf(_v0.x,(W1),A1[0]); A2[0] = fmaf(_v0.x,(W2),A2[0]); \
    A1[1] = fmaf(_v0.y,(W1),A1[1]); A2[1] = fmaf(_v0.y,(W2),A2[1]); \
    A1[2] = fmaf(_v0.z,(W1),A1[2]); A2[2] = fmaf(_v0.z,(W2),A2[2]); \
    A1[3] = fmaf(_v0.w,(W1),A1[3]); A2[3] = fmaf(_v0.w,(W2),A2[3]); \
    A1[4] = fmaf(_v1.x,(W1),A1[4]); A2[4] = fmaf(_v1.x,(W2),A2[4]); \
    A1[5] = fmaf(_v1.y,(W1),A1[5]); A2[5] = fmaf(_v1.y,(W2),A2[5]); \
    A1[6] = fmaf(_v1.z,(W1),A1[6]); A2[6] = fmaf(_v1.z,(W2),A2[6]); \
    A1[7] = fmaf(_v1.w,(W1),A1[7]); A2[7] = fmaf(_v1.w,(W2),A2[7]); \
} while (0)

// ---------- build B matrices (bf16 hi/lo 3-term layout) from f32 weights ----------
__global__ __launch_bounds__(256) void k_prep_b(
    const float* __restrict__ w0, const float* __restrict__ gw0,
    const float* __restrict__ w12, const float* __restrict__ gw12,
    unsigned short* __restrict__ b0t, unsigned short* __restrict__ b1t,
    unsigned short* __restrict__ b2t)
{
    const int n = blockIdx.x;
    const int gate = n >> 7, oo = n & 127;
    const float sgn = (gate == 1) ? -0.5f : 1.0f;
    for (int k = threadIdx.x; k < 1056; k += 256) {
        float w; int isLo;
        if (k < 672) {
            int blk = k / 224, col = k - blk * 224;
            w = (col < 200) ? w0[(size_t)(128 + col) * 512 + n] : 0.f;
            isLo = (blk == 1);
        } else {
            int kg = k - 672, blkg = kg >> 7, colg = kg & 127;
            w = sgn * gw0[(size_t)(gate * 128 + colg) * 128 + oo];
            isLo = (blkg == 1);
        }
        unsigned short hi = f2bf(w);
        b0t[(size_t)n * 1056 + k] = isLo ? f2bf(w - bf2f(hi)) : hi;
    }
    for (int l = 0; l < 2; ++l) {
        unsigned short* dst = l ? b2t : b1t;
        for (int k = threadIdx.x; k < 768; k += 256) {
            float w; int isLo;
            if (k < 384) {
                int blk = k >> 7, col = k & 127;
                w = w12[(size_t)(l * 256 + 128 + col) * 512 + n];
                isLo = (blk == 1);
            } else {
                int kg = k - 384, blkg = kg >> 7, colg = kg & 127;
                w = sgn * gw12[(size_t)((l * 4 + gate) * 128 + colg) * 128 + oo];
                isLo = (blkg == 1);
            }
            unsigned short hi = f2bf(w);
            dst[(size_t)n * 768 + k] = isLo ? f2bf(w - bf2f(hi)) : hi;
        }
    }
}

// ---------- one-time fusion-weight folding ----------
__global__ __launch_bounds__(128) void k_prep_fuse(
    const float* __restrict__ w_q, const float* __restrict__ b_q,
    const float* __restrict__ w_k, const float* __restrict__ b_k,
    const float* __restrict__ w_v, const float* __restrict__ b_v,
    const float* __restrict__ w_o,
    float* __restrict__ GT, float* __restrict__ WVO,
    float* __restrict__ e1, float* __restrict__ e2,
    float* __restrict__ e0, float* __restrict__ bvo)
{
    __shared__ float sk[128], sv[128];
    __shared__ float rtmp[8];
    const int i = blockIdx.x, f = threadIdx.x;
    sk[f] = w_k[(size_t)i * 128 + f];
    sv[f] = w_v[(size_t)i * 128 + f];
    __syncthreads();
    float g = 0.f, wv = 0.f;
    #pragma unroll 4
    for (int a = 0; a < 128; ++a) {
        g  = fmaf(w_q[(size_t)f * 128 + a], sk[a], g);
        wv = fmaf(sv[a], w_o[(size_t)a * 128 + f], wv);
    }
    GT[(size_t)i * 128 + f] = g;
    WVO[(size_t)i * 128 + f] = wv;
    float p1 = w_q[(size_t)i * 128 + f] * b_k[f];
    float p2 = sk[f] * b_q[f];
    #pragma unroll
    for (int sh = 32; sh > 0; sh >>= 1) {
        p1 += __shfl_xor(p1, sh, 64);
        p2 += __shfl_xor(p2, sh, 64);
    }
    if ((f & 63) == 0) { rtmp[(f >> 6) * 2] = p1; rtmp[(f >> 6) * 2 + 1] = p2; }
    __syncthreads();
    if (f == 0) { e1[i] = rtmp[0] + rtmp[2]; e2[i] = rtmp[1] + rtmp[3]; }
    if (i == 0) {
        float bw = 0.f;
        #pragma unroll 4
        for (int a = 0; a < 128; ++a) bw = fmaf(b_v[a], w_o[(size_t)a * 128 + f], bw);
        bvo[f] = bw;
        float p0 = b_q[f] * b_k[f];
        #pragma unroll
        for (int sh = 32; sh > 0; sh >>= 1) p0 += __shfl_xor(p0, sh, 64);
        if ((f & 63) == 0) rtmp[4 + (f >> 6)] = p0;
        __syncthreads();
        if (f == 0) e0[0] = rtmp[4] + rtmp[5];
    }
}

// ---------- folded TwoStageFusion, 256 threads (2 token-halves x 128 f) ----------
__global__ __launch_bounds__(256, 4) void k_gamma2(
    const float* __restrict__ ac, const float* __restrict__ pc,
    const float* __restrict__ rd,
    const float* __restrict__ w_amp, const float* __restrict__ b_amp,
    const float* __restrict__ w_ph,  const float* __restrict__ b_ph,
    const float* __restrict__ w_g,   const float* __restrict__ b_g,
    const float* __restrict__ w_r1,  const float* __restrict__ b_r1,
    const float* __restrict__ w_r2,  const float* __restrict__ b_r2,
    const float* __restrict__ GT,    const float* __restrict__ WVO,
    const float* __restrict__ e1,    const float* __restrict__ e2,
    const float* __restrict__ e0,    const float* __restrict__ bvo,
    const float* __restrict__ b_o,
    unsigned short* __restrict__ gsh, int segLen, int lgSeg, int tbase)
{
    __shared__ alignas(16) float catT[256][GPAD];
    __shared__ alignas(16) float rlT[128][GPAD];
    __shared__ float scin[4][16];
    __shared__ float red[2][2][8];

    const int tid = threadIdx.x;
    const int f = tid & 127;
    const int th = tid >> 7;        // token half
    const int t0 = th * 8;
    const int r0 = blockIdx.x * 16;
    const int b = r0 >> lgSeg;
    const int tl = r0 & (segLen - 1);
    const int tau0 = tbase + tl - 1;

    if (tid < 64) {
        int j = tid >> 4, tt = tid & 15;
        int tau = tau0 + tt; if (tau < 0) tau = 0;
        size_t tok = (size_t)b * TT + tau;
        float v;
        if (j == 0) v = ac[tok];
        else if (j == 1) v = pc[tok];
        else v = rd[tok * 2 + (j - 2)];
        scin[j][tt] = v;
    }
    const float wa = w_amp[f], ba = b_amp[f];
    const float wp = w_ph[f],  bpv = b_ph[f];
    const float w1a = w_r1[f], w1b = w_r1[128 + f];
    const float br1 = b_r1[f], br2v = b_r2[f];
    const float bg = b_g[f];
    __syncthreads();

    float ph8[8], am8[8];
    #pragma unroll
    for (int t = 0; t < 8; ++t) {
        float a = scin[0][t0 + t], p = scin[1][t0 + t];
        float r0v = scin[2][t0 + t], r1v = scin[3][t0 + t];
        float phv = tanh_(fmaf(p, wp, bpv));
        float amv = tanh_(fmaf(a, wa, ba));
        ph8[t] = phv; am8[t] = amv;
        catT[f][t0 + t] = phv;
        catT[128 + f][t0 + t] = amv;
        rlT[f][t0 + t] = tanh_(fmaf(r1v, w1b, fmaf(r0v, w1a, br1)));
    }
    __syncthreads();

    // pass 1: gate logits (K=256) + rlos layer2 (K=128)
    float bacc[8], racc[8];
    #pragma unroll
    for (int t = 0; t < 8; ++t) { bacc[t] = 0.f; racc[t] = 0.f; }
    #pragma unroll 2
    for (int i = 0; i < 128; ++i) {
        float wg1 = w_g[i * 128 + f];
        float wg2 = w_g[(128 + i) * 128 + f];
        float wr  = w_r2[i * 128 + f];
        MAC8(bacc, &catT[i][t0], wg1);
        MAC8(bacc, &catT[128 + i][t0], wg2);
        MAC8(racc, &rlT[i][t0], wr);
    }
    float corr8[8], rl8[8];
    #pragma unroll
    for (int t = 0; t < 8; ++t) {
        float beta = sigm(bacc[t] + bg);
        corr8[t] = fmaf(beta, ph8[t] - am8[t], am8[t]);
        rl8[t] = tanh_(racc[t] + br2v);
    }
    __syncthreads();
    #pragma unroll
    for (int t = 0; t < 8; ++t) rlT[f][t0 + t] = rl8[t];
    __syncthreads();

    // pass 2 (dual): u = G.rl  and  vo = rl.(WvWo)
    float uacc[8], voacc[8];
    #pragma unroll
    for (int t = 0; t < 8; ++t) { uacc[t] = 0.f; voacc[t] = 0.f; }
    #pragma unroll 2
    for (int i = 0; i < 128; ++i) {
        float wu = GT[i * 128 + f];
        float wv = WVO[i * 128 + f];
        MAC8_2(uacc, voacc, &rlT[i][t0], wu, wv);
    }

    const int lane = tid & 63, wv2 = (tid >> 6) & 1;
    const float e1f = e1[f], e2f = e2[f], e0v = e0[0];
    #pragma unroll
    for (int t = 0; t < 8; ++t) {
        float pdot = fmaf(corr8[t], uacc[t] + e1f, rl8[t] * e2f);
        #pragma unroll
        for (int sh = 32; sh > 0; sh >>= 1) pdot += __shfl_xor(pdot, sh, 64);
        if (lane == 0) red[th][wv2][t] = pdot;
    }
    __syncthreads();
    const float bvof = bvo[f], bof = b_o[f];
    #pragma unroll
    for (int t = 0; t < 8; ++t) {
        float attn = sigm((red[th][0][t] + red[th][1][t] + e0v) * 0.088388347648318447f);
        float g = fmaf(attn, voacc[t] + bvof, bof);
        if (tau0 + t0 + t < 0) g = 0.f;
        unsigned short hi = f2bf(g);
        gsh[(size_t)(r0 + t0 + t) * 256 + f] = hi;
        gsh[(size_t)(r0 + t0 + t) * 256 + 128 + f] = f2bf(g - bf2f(hi));
    }
}

// ---------- legacy (un-folded) fusion kernel: fallback if workspace is tight ----------
__global__ __launch_bounds__(128) void k_gamma(
    const float* __restrict__ ac, const float* __restrict__ pc,
    const float* __restrict__ rd,
    const float* __restrict__ w_amp, const float* __restrict__ b_amp,
    const float* __restrict__ w_ph,  const float* __restrict__ b_ph,
    const float* __restrict__ w_g,   const float* __restrict__ b_g,
    const float* __restrict__ w_r1,  const float* __restrict__ b_r1,
    const float* __restrict__ w_r2,  const float* __restrict__ b_r2,
    const float* __restrict__ w_q,   const float* __restrict__ b_q,
    const float* __restrict__ w_k,   const float* __restrict__ b_k,
    const float* __restrict__ w_v,   const float* __restrict__ b_v,
    const float* __restrict__ w_o,   const float* __restrict__ b_o,
    unsigned short* __restrict__ gsh, int segLen, int lgSeg, int tbase)
{
    __shared__ alignas(16) float catT[256][GPAD];
    __shared__ alignas(16) float rlT[128][GPAD];
    __shared__ alignas(16) float avT[128][GPAD];
    __shared__ float scin[4][16];
    __shared__ float red[2][16];

    const int f = threadIdx.x;
    const int r0 = blockIdx.x * 16;
    const int b = r0 >> lgSeg;
    const int tl = r0 & (segLen - 1);
    const int tau0 = tbase + tl - 1;

    if (f < 64) {
        int j = f >> 4, tt = f & 15;
        int tau = tau0 + tt; if (tau < 0) tau = 0;
        size_t tok = (size_t)b * TT + tau;
        float v;
        if (j == 0) v = ac[tok];
        else if (j == 1) v = pc[tok];
        else v = rd[tok * 2 + (j - 2)];
        scin[j][tt] = v;
    }
    const float wa = w_amp[f], ba = b_amp[f];
    const float wp = w_ph[f],  bpv = b_ph[f];
    const float w1a = w_r1[f], w1b = w_r1[128 + f];
    const float br1 = b_r1[f], br2 = b_r2[f];
    const float bg = b_g[f];
    const float bqv = b_q[f], bkv = b_k[f];
    const float bvv = b_v[f], bov = b_o[f];
    __syncthreads();

    float ph16[16], am16[16];
    #pragma unroll
    for (int t = 0; t < 16; ++t) {
        float a = scin[0][t], p = scin[1][t], r0v = scin[2][t], r1v = scin[3][t];
        float phv = tanh_(fmaf(p, wp, bpv));
        float amv = tanh_(fmaf(a, wa, ba));
        ph16[t] = phv; am16[t] = amv;
        catT[f][t] = phv;
        catT[128 + f][t] = amv;
        rlT[f][t] = tanh_(fmaf(r1v, w1b, fmaf(r0v, w1a, br1)));
    }
    __syncthreads();

    float bacc[16], racc[16];
    #pragma unroll
    for (int t = 0; t < 16; ++t) { bacc[t] = 0.f; racc[t] = 0.f; }
    #pragma unroll 2
    for (int i = 0; i < 128; ++i) {
        float wg1 = w_g[i * 128 + f];
        float wg2 = w_g[(128 + i) * 128 + f];
        float wr  = w_r2[i * 128 + f];
        MAC16(bacc, &catT[i][0], wg1);
        MAC16(bacc, &catT[128 + i][0], wg2);
        MAC16(racc, &rlT[i][0], wr);
    }
    float corr16[16], rl16[16];
    #pragma unroll
    for (int t = 0; t < 16; ++t) {
        float beta = sigm(bacc[t] + bg);
        corr16[t] = fmaf(beta, ph16[t] - am16[t], am16[t]);
        rl16[t] = tanh_(racc[t] + br2);
    }
    __syncthreads();
    #pragma unroll
    for (int t = 0; t < 16; ++t) { catT[f][t] = corr16[t]; rlT[f][t] = rl16[t]; }
    __syncthreads();

    float qa[16], ka[16], va[16];
    #pragma unroll
    for (int t = 0; t < 16; ++t) { qa[t] = 0.f; ka[t] = 0.f; va[t] = 0.f; }
    #pragma unroll 2
    for (int i = 0; i < 128; ++i) {
        float wq = w_q[i * 128 + f];
        float wk = w_k[i * 128 + f];
        float wv = w_v[i * 128 + f];
        MAC16(qa, &catT[i][0], wq);
        MAC16(ka, &rlT[i][0], wk);
        MAC16(va, &rlT[i][0], wv);
    }
    const int lane = f & 63, wvi = f >> 6;
    #pragma unroll
    for (int t = 0; t < 16; ++t) {
        float pdot = (qa[t] + bqv) * (ka[t] + bkv);
        #pragma unroll
        for (int sh = 32; sh > 0; sh >>= 1) pdot += __shfl_xor(pdot, sh, 64);
        if (lane == 0) red[wvi][t] = pdot;
    }
    __syncthreads();
    #pragma unroll
    for (int t = 0; t < 16; ++t) {
        float attn = sigm((red[0][t] + red[1][t]) * 0.088388347648318447f);
        avT[f][t] = attn * (va[t] + bvv);
    }
    __syncthreads();
    float oacc[16];
    #pragma unroll
    for (int t = 0; t < 16; ++t) oacc[t] = 0.f;
    #pragma unroll 2
    for (int i = 0; i < 128; ++i) {
        float wo = w_o[i * 128 + f];
        MAC16(oacc, &avT[i][0], wo);
    }
    #pragma unroll
    for (int t = 0; t < 16; ++t) {
        float g = oacc[t] + bov;
        if (tau0 + t < 0) g = 0.f;
        unsigned short hi = f2bf(g);
        gsh[(size_t)(r0 + t) * 256 + f] = hi;
        gsh[(size_t)(r0 + t) * 256 + 128 + f] = f2bf(g - bf2f(hi));
    }
}

// ---------- stage |hrrp| into bf16 hi/lo ----------
__global__ __launch_bounds__(256) void k_stagex(
    const float* __restrict__ hrrp, unsigned short* __restrict__ xs,
    int segLen, int lgSeg, int tbase)
{
    const int m = blockIdx.x;
    const int b = m >> lgSeg, tl = m & (segLen - 1);
    const size_t bt = (size_t)b * TT + tbase + tl;
    const int col = threadIdx.x;
    if (col < 224) {
        float v = (col < 200) ? fabsf(hrrp[bt * DD + col]) : 0.f;
        unsigned short hi = f2bf(v);
        xs[(size_t)m * 448 + col] = hi;
        xs[(size_t)m * 448 + 224 + col] = f2bf(v - bf2f(hi));
    }
}

// ---------- A-fragment address for 3-term layout ----------
template<int KTOT>
__device__ __forceinline__ const unsigned short* addrA(
    const unsigned short* __restrict__ Ax, const unsigned short* __restrict__ Ag,
    int m, int ko)
{
    if (KTOT == 1056) {
        if (ko < 672) {
            int blk = ko / 224, col = ko - blk * 224;
            return Ax + (size_t)m * 448 + (blk == 2 ? 224 : 0) + col;
        }
        int kg = ko - 672, blkg = kg >> 7, colg = kg & 127;
        return Ag + (size_t)m * 256 + (blkg == 2 ? 128 : 0) + colg;
    } else {
        if (ko < 384) {
            int blk = ko >> 7, col = ko & 127;
            return Ax + (size_t)m * 256 + (blk == 2 ? 128 : 0) + col;
        }
        int kg = ko - 384, blkg = kg >> 7, colg = kg & 127;
        return Ag + (size_t)m * 256 + (blkg == 2 ? 128 : 0) + colg;
    }
}

// ---------- bf16 MFMA GEMM (+bias[n]), global_load_lds double-buffered ----------
template<int KTOT>
__global__ __launch_bounds__(256) void k_gemm(
    const unsigned short* __restrict__ Ax, const unsigned short* __restrict__ Ag,
    const unsigned short* __restrict__ Bt, const float* __restrict__ bp,
    float* __restrict__ C)
{
    __shared__ alignas(16) unsigned short Als[2][4096];
    __shared__ alignas(16) unsigned short Bls[2][4096];
    const int tid = threadIdx.x;
    const int m0 = blockIdx.x * 128, n0 = blockIdx.y * 128;
    const int wave = tid >> 6, lane = tid & 63;
    const int lm = lane & 15, lq = lane >> 4;
    const int wm = wave >> 1, wn = wave & 1;
    const int srow = tid >> 2, scol = (tid & 3) * 8;
    const int wb = wave * 512;

    const f32x4 vzero = {0.f, 0.f, 0.f, 0.f};
    f32x4 acc[4][4];
    #pragma unroll
    for (int x = 0; x < 4; ++x)
        #pragma unroll
        for (int y = 0; y < 4; ++y) acc[x][y] = vzero;

    float bn[4];
    #pragma unroll
    for (int nt = 0; nt < 4; ++nt) bn[nt] = bp[n0 + wn * 64 + nt * 16 + lm];

    constexpr int NKB = KTOT / 32;

    #define STAGE(buf, kb) do { \
        const int _ko = (kb) * 32 + scol; \
        gll16(addrA<KTOT>(Ax, Ag, m0 + srow, _ko),        &Als[buf][wb]); \
        gll16(addrA<KTOT>(Ax, Ag, m0 + 64 + srow, _ko),   &Als[buf][2048 + wb]); \
        gll16(Bt + (size_t)(n0 + srow) * KTOT + _ko,      &Bls[buf][wb]); \
        gll16(Bt + (size_t)(n0 + 64 + srow) * KTOT + _ko, &Bls[buf][2048 + wb]); \
    } while (0)

    STAGE(0, 0);
    __syncthreads();
    int cur = 0;
    for (int kb = 0; kb < NKB; ++kb) {
        if (kb + 1 < NKB) STAGE(cur ^ 1, kb + 1);
        bf16x8 af[4], bfr[4];
        #pragma unroll
        for (int mt = 0; mt < 4; ++mt)
            af[mt] = *(const bf16x8*)&Als[cur][(wm * 64 + mt * 16 + lm) * 32 + lq * 8];
        #pragma unroll
        for (int nt = 0; nt < 4; ++nt)
            bfr[nt] = *(const bf16x8*)&Bls[cur][(wn * 64 + nt * 16 + lm) * 32 + lq * 8];
        #pragma unroll
        for (int mt = 0; mt < 4; ++mt)
            #pragma unroll
            for (int nt = 0; nt < 4; ++nt)
                acc[mt][nt] = __builtin_amdgcn_mfma_f32_16x16x32_bf16(af[mt], bfr[nt], acc[mt][nt], 0, 0, 0);
        __syncthreads();
        cur ^= 1;
    }
    #undef STAGE

    #pragma unroll
    for (int mt = 0; mt < 4; ++mt) {
        #pragma unroll
        for (int nt = 0; nt < 4; ++nt) {
            const int m = m0 + wm * 64 + mt * 16 + lq * 4;
            const int n = n0 + wn * 64 + nt * 16 + lm;
            #pragma unroll
            for (int r = 0; r < 4; ++r)
                C[(size_t)(m + r) * 512 + n] = acc[mt][nt][r] + bn[nt];
        }
    }
}

// ---------- recurrent scan, K-split over 1024 threads; weights VGPR-resident ----------
// thread (kh = tid>>9, o = tid&511) accumulates z-partial over h[kh*64 .. kh*64+64)
// pre already contains bias (added by k_gemm).
template<int STORE_XH, int FINAL>
__global__ __launch_bounds__(1024, 4) void k_scan2(
    const float* __restrict__ pre, const float* __restrict__ Wh,
    float* __restrict__ st_h, float* __restrict__ st_c,
    unsigned short* __restrict__ xh, float* __restrict__ outp,
    const float* __restrict__ regw, const float* __restrict__ regb,
    int first, int R)
{
    const int tid = threadIdx.x;
    const int o = tid & 511;
    const int kh = tid >> 9;           // uniform per wave (waves 0-7: 0, 8-15: 1)
    const int b = blockIdx.x;
    __shared__ alignas(16) float hbuf[128];
    __shared__ float zbuf[1024];

    // 64 weights / thread -> register-resident under VGPR cap 128
    float wc[64];
    #pragma unroll
    for (int i = 0; i < 64; ++i) wc[i] = Wh[(size_t)(kh * 64 + i) * 512 + o];

    float c = 0.f;
    if (tid < 128) {
        float h0 = 0.f;
        if (!first) { h0 = st_h[b * 128 + tid]; c = st_c[b * 128 + tid]; }
        hbuf[tid] = h0;
    }
    __syncthreads();

    const float* preb = pre + (size_t)b * R * 512;
    float p = (kh == 0) ? preb[o] : 0.f;
    for (int t = 0; t < R; ++t) {
        float q = 0.f;
        if (kh == 0 && t < R - 1) q = preb[(size_t)(t + 1) * 512 + o];
        float acc_a = p, acc_b = 0.f;
        const float* hb = &hbuf[kh * 64];
        #pragma unroll
        for (int i8 = 0; i8 < 8; ++i8) {
            const float4 ha = *(const float4*)&hb[i8 * 8];
            const float4 hc = *(const float4*)&hb[i8 * 8 + 4];
            acc_a = fmaf(ha.x, wc[i8 * 8 + 0], acc_a);
            acc_b = fmaf(hc.x, wc[i8 * 8 + 4], acc_b);
            acc_a = fmaf(ha.y, wc[i8 * 8 + 1], acc_a);
            acc_b = fmaf(hc.y, wc[i8 * 8 + 5], acc_b);
            acc_a = fmaf(ha.z, wc[i8 * 8 + 2], acc_a);
            acc_b = fmaf(hc.z, wc[i8 * 8 + 6], acc_b);
            acc_a = fmaf(ha.w, wc[i8 * 8 + 3], acc_a);
            acc_b = fmaf(hc.w, wc[i8 * 8 + 7], acc_b);
        }
        zbuf[tid] = acc_a + acc_b;
        __syncthreads();
        if (tid < 128) {
            const float zi = zbuf[tid]       + zbuf[512 + tid];
            const float zf = zbuf[tid + 128] + zbuf[512 + tid + 128];
            const float zc = zbuf[tid + 256] + zbuf[512 + tid + 256];
            const float zo = zbuf[tid + 384] + zbuf[512 + tid + 384];
            const float ig = sigm(zi);
            const float fg = sigm(zf);
            const float ch = tanh_(zc);
            const float og = sigm(zo);
            c = fg * c + ig * ch;
            const float h2 = og * tanh_(c);
            hbuf[tid] = h2;
            if (STORE_XH) {
                unsigned short hi = f2bf(h2);
                size_t row = (size_t)b * R + t;
                xh[row * 256 + tid] = hi;
                xh[row * 256 + 128 + tid] = f2bf(h2 - bf2f(hi));
            }
        }
        __syncthreads();
        p = q;
    }
    if (tid < 128) { st_h[b * 128 + tid] = hbuf[tid]; st_c[b * 128 + tid] = c; }
    if (FINAL && tid < 2) {
        float s = regb[tid];
        #pragma unroll 4
        for (int i = 0; i < 128; ++i) s = fmaf(hbuf[i], regw[i * 2 + tid], s);
        outp[b * 2 + tid] = s;   // f32 output
    }
}

// ---------- host ----------
extern "C" void kernel_launch(void* const* d_in, const int* in_sizes, int n_in,
                              void* d_out, int out_size, void* d_ws, size_t ws_size,
                              hipStream_t stream)
{
    const float* hrrp = (const float*)d_in[0];
    const float* ac   = (const float*)d_in[1];
    const float* pc   = (const float*)d_in[2];
    const float* rd   = (const float*)d_in[3];
    const float* w_amp= (const float*)d_in[4];
    const float* b_amp= (const float*)d_in[5];
    const float* w_ph = (const float*)d_in[6];
    const float* b_ph = (const float*)d_in[7];
    const float* w_g  = (const float*)d_in[8];
    const float* b_g  = (const float*)d_in[9];
    const float* w_r1 = (const float*)d_in[10];
    const float* b_r1 = (const float*)d_in[11];
    const float* w_r2 = (const float*)d_in[12];
    const float* b_r2 = (const float*)d_in[13];
    const float* w_q  = (const float*)d_in[14];
    const float* b_q  = (const float*)d_in[15];
    const float* w_k  = (const float*)d_in[16];
    const float* b_k  = (const float*)d_in[17];
    const float* w_v  = (const float*)d_in[18];
    const float* b_v  = (const float*)d_in[19];
    const float* w_o  = (const float*)d_in[20];
    const float* b_o  = (const float*)d_in[21];
    const float* w0   = (const float*)d_in[22];
    const float* b0   = (const float*)d_in[23];
    const float* gw0  = (const float*)d_in[24];
    const float* w12  = (const float*)d_in[25];
    const float* b12  = (const float*)d_in[26];
    const float* gw12 = (const float*)d_in[27];
    const float* regw = (const float*)d_in[28];
    const float* regb = (const float*)d_in[29];
    float* outp = (float*)d_out;

    const size_t need64 = 68452352ULL, need32 = 35946496ULL;
    const size_t EXTRA = 132864ULL;     // GT + WVO + e1 + e2 + bvo + e0
    int R, lg, folded;
    if      (ws_size >= need64 + EXTRA) { R = 64; lg = 6; folded = 1; }
    else if (ws_size >= need64)         { R = 64; lg = 6; folded = 0; }
    else if (ws_size >= need32 + EXTRA) { R = 32; lg = 5; folded = 1; }
    else if (ws_size >= need32)         { R = 32; lg = 5; folded = 0; }
    else return;
    const int NSEG = TT / R;
    const int MR = BB * R;

    char* ws = (char*)d_ws;
    size_t off = 0;
    float* pre = (float*)(ws + off);                   off += (size_t)MR * 512 * 4;
    unsigned short* gsh = (unsigned short*)(ws + off); off += (size_t)MR * 256 * 2;
    unsigned short* xh  = (unsigned short*)(ws + off); off += (size_t)MR * 256 * 2;
    unsigned short* xs  = (unsigned short*)(ws + off); off += (size_t)MR * 448 * 2;
    float* sh0 = (float*)(ws + off); off += 131072;
    float* sc0 = (float*)(ws + off); off += 131072;
    float* sh1 = (float*)(ws + off); off += 131072;
    float* sc1 = (float*)(ws + off); off += 131072;
    float* sh2 = (float*)(ws + off); off += 131072;
    float* sc2 = (float*)(ws + off); off += 131072;
    unsigned short* b0t = (unsigned short*)(ws + off); off += 512 * 1056 * 2;
    unsigned short* b1t = (unsigned short*)(ws + off); off += 512 * 768 * 2;
    unsigned short* b2t = (unsigned short*)(ws + off); off += 512 * 768 * 2;
    float* GT = nullptr; float* WVO = nullptr;
    float* e1p = nullptr; float* e2p = nullptr; float* bvop = nullptr; float* e0p = nullptr;
    if (folded) {
        GT   = (float*)(ws + off); off += 128 * 128 * 4;
        WVO  = (float*)(ws + off); off += 128 * 128 * 4;
        e1p  = (float*)(ws + off); off += 512;
        e2p  = (float*)(ws + off); off += 512;
        bvop = (float*)(ws + off); off += 512;
        e0p  = (float*)(ws + off); off += 256;
    }

    k_prep_b<<<512, 256, 0, stream>>>(w0, gw0, w12, gw12, b0t, b1t, b2t);
    if (folded)
        k_prep_fuse<<<128, 128, 0, stream>>>(w_q, b_q, w_k, b_k, w_v, b_v, w_o,
                                             GT, WVO, e1p, e2p, e0p, bvop);

    for (int seg = 0; seg < NSEG; ++seg) {
        const int first = (seg == 0) ? 1 : 0;
        const int tbase = seg * R;
        if (folded)
            k_gamma2<<<MR / 16, 256, 0, stream>>>(ac, pc, rd, w_amp, b_amp, w_ph, b_ph,
                                                  w_g, b_g, w_r1, b_r1, w_r2, b_r2,
                                                  GT, WVO, e1p, e2p, e0p, bvop, b_o,
                                                  gsh, R, lg, tbase);
        else
            k_gamma<<<MR / 16, 128, 0, stream>>>(ac, pc, rd, w_amp, b_amp, w_ph, b_ph,
                                                 w_g, b_g, w_r1, b_r1, w_r2, b_r2,
                                                 w_q, b_q, w_k, b_k, w_v, b_v, w_o, b_o,
                                                 gsh, R, lg, tbase);
        k_stagex<<<MR, 256, 0, stream>>>(hrrp, xs, R, lg, tbase);
        // layer 0
        k_gemm<1056><<<dim3(MR / 128, 4), 256, 0, stream>>>(xs, gsh, b0t, b0, pre);
        k_scan2<1, 0><<<BB, 1024, 0, stream>>>(pre, w0, sh0, sc0, xh,
                                               nullptr, nullptr, nullptr, first, R);
        // layer 1
        k_gemm<768><<<dim3(MR / 128, 4), 256, 0, stream>>>(xh, gsh, b1t, b12, pre);
        k_scan2<1, 0><<<BB, 1024, 0, stream>>>(pre, w12, sh1, sc1, xh,
                                               nullptr, nullptr, nullptr, first, R);
        // layer 2
        k_gemm<768><<<dim3(MR / 128, 4), 256, 0, stream>>>(xh, gsh, b2t, b12 + 512, pre);
        if (seg < NSEG - 1)
            k_scan2<0, 0><<<BB, 1024, 0, stream>>>(pre, w12 + 256 * 512, sh2, sc2,
                                                   nullptr, nullptr, nullptr, nullptr, first, R);
        else
            k_scan2<0, 1><<<BB, 1024, 0, stream>>>(pre, w12 + 256 * 512, sh2, sc2,
                                                   nullptr, outp, regw, regb, first, R);
    }
}

// Round 5
// 2753.533 us; speedup vs baseline: 1.9949x; 1.1537x over previous
//
#include <hip/hip_runtime.h>

#define BB 256
#define TT 512
#define DD 200

// ---------- helpers ----------
__device__ __forceinline__ float bf2f(unsigned short u) {
    return __uint_as_float(((unsigned int)u) << 16);
}
__device__ __forceinline__ unsigned short f2bf(float f) {
    unsigned int u = __float_as_uint(f);
    u += 0x7FFFu + ((u >> 16) & 1u);
    return (unsigned short)(u >> 16);
}
__device__ __forceinline__ float sigm(float x) { return 1.0f / (1.0f + __expf(-x)); }
__device__ __forceinline__ float tanh_(float x) { return 1.0f - 2.0f / (__expf(2.0f * x) + 1.0f); }

typedef __bf16 bf16x8 __attribute__((ext_vector_type(8)));
typedef float  f32x4  __attribute__((ext_vector_type(4)));

#define GPAD 20

// async global->LDS 16B (dest = wave-uniform base + lane*16)
__device__ __forceinline__ void gll16(const unsigned short* g, unsigned short* l) {
    __builtin_amdgcn_global_load_lds(
        (const __attribute__((address_space(1))) unsigned int*)g,
        (__attribute__((address_space(3))) unsigned int*)l,
        16, 0, 0);
}

#define MAC16(ACCV, BASE, W) do { \
    const float4* _p4 = (const float4*)(BASE); \
    float4 _v0 = _p4[0], _v1 = _p4[1], _v2 = _p4[2], _v3 = _p4[3]; \
    ACCV[0]  = fmaf(_v0.x,(W),ACCV[0]);  ACCV[1]  = fmaf(_v0.y,(W),ACCV[1]); \
    ACCV[2]  = fmaf(_v0.z,(W),ACCV[2]);  ACCV[3]  = fmaf(_v0.w,(W),ACCV[3]); \
    ACCV[4]  = fmaf(_v1.x,(W),ACCV[4]);  ACCV[5]  = fmaf(_v1.y,(W),ACCV[5]); \
    ACCV[6]  = fmaf(_v1.z,(W),ACCV[6]);  ACCV[7]  = fmaf(_v1.w,(W),ACCV[7]); \
    ACCV[8]  = fmaf(_v2.x,(W),ACCV[8]);  ACCV[9]  = fmaf(_v2.y,(W),ACCV[9]); \
    ACCV[10] = fmaf(_v2.z,(W),ACCV[10]); ACCV[11] = fmaf(_v2.w,(W),ACCV[11]); \
    ACCV[12] = fmaf(_v3.x,(W),ACCV[12]); ACCV[13] = fmaf(_v3.y,(W),ACCV[13]); \
    ACCV[14] = fmaf(_v3.z,(W),ACCV[14]); ACCV[15] = fmaf(_v3.w,(W),ACCV[15]); \
} while (0)

#define MAC8(ACCV, BASE, W) do { \
    const float4* _p4 = (const float4*)(BASE); \
    float4 _v0 = _p4[0], _v1 = _p4[1]; \
    ACCV[0] = fmaf(_v0.x,(W),ACCV[0]); ACCV[1] = fmaf(_v0.y,(W),ACCV[1]); \
    ACCV[2] = fmaf(_v0.z,(W),ACCV[2]); ACCV[3] = fmaf(_v0.w,(W),ACCV[3]); \
    ACCV[4] = fmaf(_v1.x,(W),ACCV[4]); ACCV[5] = fmaf(_v1.y,(W),ACCV[5]); \
    ACCV[6] = fmaf(_v1.z,(W),ACCV[6]); ACCV[7] = fmaf(_v1.w,(W),ACCV[7]); \
} while (0)

#define MAC8_2(A1, A2, BASE, W1, W2) do { \
    const float4* _p4 = (const float4*)(BASE); \
    float4 _v0 = _p4[0], _v1 = _p4[1]; \
    A1[0] = fmaf(_v0.x,(W1),A1[0]); A2[0] = fmaf(_v0.x,(W2),A2[0]); \
    A1[1] = fmaf(_v0.y,(W1),A1[1]); A2[1] = fmaf(_v0.y,(W2),A2[1]); \
    A1[2] = fmaf(_v0.z,(W1),A1[2]); A2[2] = fmaf(_v0.z,(W2),A2[2]); \
    A1[3] = fmaf(_v0.w,(W1),A1[3]); A2[3] = fmaf(_v0.w,(W2),A2[3]); \
    A1[4] = fmaf(_v1.x,(W1),A1[4]); A2[4] = fmaf(_v1.x,(W2),A2[4]); \
    A1[5] = fmaf(_v1.y,(W1),A1[5]); A2[5] = fmaf(_v1.y,(W2),A2[5]); \
    A1[6] = fmaf(_v1.z,(W1),A1[6]); A2[6] = fmaf(_v1.z,(W2),A2[6]); \
    A1[7] = fmaf(_v1.w,(W1),A1[7]); A2[7] = fmaf(_v1.w,(W2),A2[7]); \
} while (0)

// ---------- build B matrices (bf16 hi/lo 3-term layout) from f32 weights ----------
__global__ __launch_bounds__(256) void k_prep_b(
    const float* __restrict__ w0, const float* __restrict__ gw0,
    const float* __restrict__ w12, const float* __restrict__ gw12,
    unsigned short* __restrict__ b0t, unsigned short* __restrict__ b1t,
    unsigned short* __restrict__ b2t)
{
    const int n = blockIdx.x;
    const int gate = n >> 7, oo = n & 127;
    const float sgn = (gate == 1) ? -0.5f : 1.0f;
    for (int k = threadIdx.x; k < 1056; k += 256) {
        float w; int isLo;
        if (k < 672) {
            int blk = k / 224, col = k - blk * 224;
            w = (col < 200) ? w0[(size_t)(128 + col) * 512 + n] : 0.f;
            isLo = (blk == 1);
        } else {
            int kg = k - 672, blkg = kg >> 7, colg = kg & 127;
            w = sgn * gw0[(size_t)(gate * 128 + colg) * 128 + oo];
            isLo = (blkg == 1);
        }
        unsigned short hi = f2bf(w);
        b0t[(size_t)n * 1056 + k] = isLo ? f2bf(w - bf2f(hi)) : hi;
    }
    for (int l = 0; l < 2; ++l) {
        unsigned short* dst = l ? b2t : b1t;
        for (int k = threadIdx.x; k < 768; k += 256) {
            float w; int isLo;
            if (k < 384) {
                int blk = k >> 7, col = k & 127;
                w = w12[(size_t)(l * 256 + 128 + col) * 512 + n];
                isLo = (blk == 1);
            } else {
                int kg = k - 384, blkg = kg >> 7, colg = kg & 127;
                w = sgn * gw12[(size_t)((l * 4 + gate) * 128 + colg) * 128 + oo];
                isLo = (blkg == 1);
            }
            unsigned short hi = f2bf(w);
            dst[(size_t)n * 768 + k] = isLo ? f2bf(w - bf2f(hi)) : hi;
        }
    }
}

// ---------- one-time fusion-weight folding ----------
__global__ __launch_bounds__(128) void k_prep_fuse(
    const float* __restrict__ w_q, const float* __restrict__ b_q,
    const float* __restrict__ w_k, const float* __restrict__ b_k,
    const float* __restrict__ w_v, const float* __restrict__ b_v,
    const float* __restrict__ w_o,
    float* __restrict__ GT, float* __restrict__ WVO,
    float* __restrict__ e1, float* __restrict__ e2,
    float* __restrict__ e0, float* __restrict__ bvo)
{
    __shared__ float sk[128], sv[128];
    __shared__ float rtmp[8];
    const int i = blockIdx.x, f = threadIdx.x;
    sk[f] = w_k[(size_t)i * 128 + f];
    sv[f] = w_v[(size_t)i * 128 + f];
    __syncthreads();
    float g = 0.f, wv = 0.f;
    #pragma unroll 4
    for (int a = 0; a < 128; ++a) {
        g  = fmaf(w_q[(size_t)f * 128 + a], sk[a], g);
        wv = fmaf(sv[a], w_o[(size_t)a * 128 + f], wv);
    }
    GT[(size_t)i * 128 + f] = g;
    WVO[(size_t)i * 128 + f] = wv;
    float p1 = w_q[(size_t)i * 128 + f] * b_k[f];
    float p2 = sk[f] * b_q[f];
    #pragma unroll
    for (int sh = 32; sh > 0; sh >>= 1) {
        p1 += __shfl_xor(p1, sh, 64);
        p2 += __shfl_xor(p2, sh, 64);
    }
    if ((f & 63) == 0) { rtmp[(f >> 6) * 2] = p1; rtmp[(f >> 6) * 2 + 1] = p2; }
    __syncthreads();
    if (f == 0) { e1[i] = rtmp[0] + rtmp[2]; e2[i] = rtmp[1] + rtmp[3]; }
    if (i == 0) {
        float bw = 0.f;
        #pragma unroll 4
        for (int a = 0; a < 128; ++a) bw = fmaf(b_v[a], w_o[(size_t)a * 128 + f], bw);
        bvo[f] = bw;
        float p0 = b_q[f] * b_k[f];
        #pragma unroll
        for (int sh = 32; sh > 0; sh >>= 1) p0 += __shfl_xor(p0, sh, 64);
        if ((f & 63) == 0) rtmp[4 + (f >> 6)] = p0;
        __syncthreads();
        if (f == 0) e0[0] = rtmp[4] + rtmp[5];
    }
}

// ---------- folded TwoStageFusion, 256 threads (2 token-halves x 128 f) ----------
__global__ __launch_bounds__(256, 4) void k_gamma2(
    const float* __restrict__ ac, const float* __restrict__ pc,
    const float* __restrict__ rd,
    const float* __restrict__ w_amp, const float* __restrict__ b_amp,
    const float* __restrict__ w_ph,  const float* __restrict__ b_ph,
    const float* __restrict__ w_g,   const float* __restrict__ b_g,
    const float* __restrict__ w_r1,  const float* __restrict__ b_r1,
    const float* __restrict__ w_r2,  const float* __restrict__ b_r2,
    const float* __restrict__ GT,    const float* __restrict__ WVO,
    const float* __restrict__ e1,    const float* __restrict__ e2,
    const float* __restrict__ e0,    const float* __restrict__ bvo,
    const float* __restrict__ b_o,
    unsigned short* __restrict__ gsh, int segLen, int lgSeg, int tbase)
{
    __shared__ alignas(16) float catT[256][GPAD];
    __shared__ alignas(16) float rlT[128][GPAD];
    __shared__ float scin[4][16];
    __shared__ float red[2][2][8];

    const int tid = threadIdx.x;
    const int f = tid & 127;
    const int th = tid >> 7;        // token half
    const int t0 = th * 8;
    const int r0 = blockIdx.x * 16;
    const int b = r0 >> lgSeg;
    const int tl = r0 & (segLen - 1);
    const int tau0 = tbase + tl - 1;

    if (tid < 64) {
        int j = tid >> 4, tt = tid & 15;
        int tau = tau0 + tt; if (tau < 0) tau = 0;
        size_t tok = (size_t)b * TT + tau;
        float v;
        if (j == 0) v = ac[tok];
        else if (j == 1) v = pc[tok];
        else v = rd[tok * 2 + (j - 2)];
        scin[j][tt] = v;
    }
    const float wa = w_amp[f], ba = b_amp[f];
    const float wp = w_ph[f],  bpv = b_ph[f];
    const float w1a = w_r1[f], w1b = w_r1[128 + f];
    const float br1 = b_r1[f], br2v = b_r2[f];
    const float bg = b_g[f];
    __syncthreads();

    float ph8[8], am8[8];
    #pragma unroll
    for (int t = 0; t < 8; ++t) {
        float a = scin[0][t0 + t], p = scin[1][t0 + t];
        float r0v = scin[2][t0 + t], r1v = scin[3][t0 + t];
        float phv = tanh_(fmaf(p, wp, bpv));
        float amv = tanh_(fmaf(a, wa, ba));
        ph8[t] = phv; am8[t] = amv;
        catT[f][t0 + t] = phv;
        catT[128 + f][t0 + t] = amv;
        rlT[f][t0 + t] = tanh_(fmaf(r1v, w1b, fmaf(r0v, w1a, br1)));
    }
    __syncthreads();

    // pass 1: gate logits (K=256) + rlos layer2 (K=128)
    float bacc[8], racc[8];
    #pragma unroll
    for (int t = 0; t < 8; ++t) { bacc[t] = 0.f; racc[t] = 0.f; }
    #pragma unroll 2
    for (int i = 0; i < 128; ++i) {
        float wg1 = w_g[i * 128 + f];
        float wg2 = w_g[(128 + i) * 128 + f];
        float wr  = w_r2[i * 128 + f];
        MAC8(bacc, &catT[i][t0], wg1);
        MAC8(bacc, &catT[128 + i][t0], wg2);
        MAC8(racc, &rlT[i][t0], wr);
    }
    float corr8[8], rl8[8];
    #pragma unroll
    for (int t = 0; t < 8; ++t) {
        float beta = sigm(bacc[t] + bg);
        corr8[t] = fmaf(beta, ph8[t] - am8[t], am8[t]);
        rl8[t] = tanh_(racc[t] + br2v);
    }
    __syncthreads();
    #pragma unroll
    for (int t = 0; t < 8; ++t) rlT[f][t0 + t] = rl8[t];
    __syncthreads();

    // pass 2 (dual): u = G.rl  and  vo = rl.(WvWo)
    float uacc[8], voacc[8];
    #pragma unroll
    for (int t = 0; t < 8; ++t) { uacc[t] = 0.f; voacc[t] = 0.f; }
    #pragma unroll 2
    for (int i = 0; i < 128; ++i) {
        float wu = GT[i * 128 + f];
        float wv = WVO[i * 128 + f];
        MAC8_2(uacc, voacc, &rlT[i][t0], wu, wv);
    }

    const int lane = tid & 63, wv2 = (tid >> 6) & 1;
    const float e1f = e1[f], e2f = e2[f], e0v = e0[0];
    #pragma unroll
    for (int t = 0; t < 8; ++t) {
        float pdot = fmaf(corr8[t], uacc[t] + e1f, rl8[t] * e2f);
        #pragma unroll
        for (int sh = 32; sh > 0; sh >>= 1) pdot += __shfl_xor(pdot, sh, 64);
        if (lane == 0) red[th][wv2][t] = pdot;
    }
    __syncthreads();
    const float bvof = bvo[f], bof = b_o[f];
    #pragma unroll
    for (int t = 0; t < 8; ++t) {
        float attn = sigm((red[th][0][t] + red[th][1][t] + e0v) * 0.088388347648318447f);
        float g = fmaf(attn, voacc[t] + bvof, bof);
        if (tau0 + t0 + t < 0) g = 0.f;
        unsigned short hi = f2bf(g);
        gsh[(size_t)(r0 + t0 + t) * 256 + f] = hi;
        gsh[(size_t)(r0 + t0 + t) * 256 + 128 + f] = f2bf(g - bf2f(hi));
    }
}

// ---------- legacy (un-folded) fusion kernel: fallback if workspace is tight ----------
__global__ __launch_bounds__(128) void k_gamma(
    const float* __restrict__ ac, const float* __restrict__ pc,
    const float* __restrict__ rd,
    const float* __restrict__ w_amp, const float* __restrict__ b_amp,
    const float* __restrict__ w_ph,  const float* __restrict__ b_ph,
    const float* __restrict__ w_g,   const float* __restrict__ b_g,
    const float* __restrict__ w_r1,  const float* __restrict__ b_r1,
    const float* __restrict__ w_r2,  const float* __restrict__ b_r2,
    const float* __restrict__ w_q,   const float* __restrict__ b_q,
    const float* __restrict__ w_k,   const float* __restrict__ b_k,
    const float* __restrict__ w_v,   const float* __restrict__ b_v,
    const float* __restrict__ w_o,   const float* __restrict__ b_o,
    unsigned short* __restrict__ gsh, int segLen, int lgSeg, int tbase)
{
    __shared__ alignas(16) float catT[256][GPAD];
    __shared__ alignas(16) float rlT[128][GPAD];
    __shared__ alignas(16) float avT[128][GPAD];
    __shared__ float scin[4][16];
    __shared__ float red[2][16];

    const int f = threadIdx.x;
    const int r0 = blockIdx.x * 16;
    const int b = r0 >> lgSeg;
    const int tl = r0 & (segLen - 1);
    const int tau0 = tbase + tl - 1;

    if (f < 64) {
        int j = f >> 4, tt = f & 15;
        int tau = tau0 + tt; if (tau < 0) tau = 0;
        size_t tok = (size_t)b * TT + tau;
        float v;
        if (j == 0) v = ac[tok];
        else if (j == 1) v = pc[tok];
        else v = rd[tok * 2 + (j - 2)];
        scin[j][tt] = v;
    }
    const float wa = w_amp[f], ba = b_amp[f];
    const float wp = w_ph[f],  bpv = b_ph[f];
    const float w1a = w_r1[f], w1b = w_r1[128 + f];
    const float br1 = b_r1[f], br2 = b_r2[f];
    const float bg = b_g[f];
    const float bqv = b_q[f], bkv = b_k[f];
    const float bvv = b_v[f], bov = b_o[f];
    __syncthreads();

    float ph16[16], am16[16];
    #pragma unroll
    for (int t = 0; t < 16; ++t) {
        float a = scin[0][t], p = scin[1][t], r0v = scin[2][t], r1v = scin[3][t];
        float phv = tanh_(fmaf(p, wp, bpv));
        float amv = tanh_(fmaf(a, wa, ba));
        ph16[t] = phv; am16[t] = amv;
        catT[f][t] = phv;
        catT[128 + f][t] = amv;
        rlT[f][t] = tanh_(fmaf(r1v, w1b, fmaf(r0v, w1a, br1)));
    }
    __syncthreads();

    float bacc[16], racc[16];
    #pragma unroll
    for (int t = 0; t < 16; ++t) { bacc[t] = 0.f; racc[t] = 0.f; }
    #pragma unroll 2
    for (int i = 0; i < 128; ++i) {
        float wg1 = w_g[i * 128 + f];
        float wg2 = w_g[(128 + i) * 128 + f];
        float wr  = w_r2[i * 128 + f];
        MAC16(bacc, &catT[i][0], wg1);
        MAC16(bacc, &catT[128 + i][0], wg2);
        MAC16(racc, &rlT[i][0], wr);
    }
    float corr16[16], rl16[16];
    #pragma unroll
    for (int t = 0; t < 16; ++t) {
        float beta = sigm(bacc[t] + bg);
        corr16[t] = fmaf(beta, ph16[t] - am16[t], am16[t]);
        rl16[t] = tanh_(racc[t] + br2);
    }
    __syncthreads();
    #pragma unroll
    for (int t = 0; t < 16; ++t) { catT[f][t] = corr16[t]; rlT[f][t] = rl16[t]; }
    __syncthreads();

    float qa[16], ka[16], va[16];
    #pragma unroll
    for (int t = 0; t < 16; ++t) { qa[t] = 0.f; ka[t] = 0.f; va[t] = 0.f; }
    #pragma unroll 2
    for (int i = 0; i < 128; ++i) {
        float wq = w_q[i * 128 + f];
        float wk = w_k[i * 128 + f];
        float wv = w_v[i * 128 + f];
        MAC16(qa, &catT[i][0], wq);
        MAC16(ka, &rlT[i][0], wk);
        MAC16(va, &rlT[i][0], wv);
    }
    const int lane = f & 63, wvi = f >> 6;
    #pragma unroll
    for (int t = 0; t < 16; ++t) {
        float pdot = (qa[t] + bqv) * (ka[t] + bkv);
        #pragma unroll
        for (int sh = 32; sh > 0; sh >>= 1) pdot += __shfl_xor(pdot, sh, 64);
        if (lane == 0) red[wvi][t] = pdot;
    }
    __syncthreads();
    #pragma unroll
    for (int t = 0; t < 16; ++t) {
        float attn = sigm((red[0][t] + red[1][t]) * 0.088388347648318447f);
        avT[f][t] = attn * (va[t] + bvv);
    }
    __syncthreads();
    float oacc[16];
    #pragma unroll
    for (int t = 0; t < 16; ++t) oacc[t] = 0.f;
    #pragma unroll 2
    for (int i = 0; i < 128; ++i) {
        float wo = w_o[i * 128 + f];
        MAC16(oacc, &avT[i][0], wo);
    }
    #pragma unroll
    for (int t = 0; t < 16; ++t) {
        float g = oacc[t] + bov;
        if (tau0 + t < 0) g = 0.f;
        unsigned short hi = f2bf(g);
        gsh[(size_t)(r0 + t) * 256 + f] = hi;
        gsh[(size_t)(r0 + t) * 256 + 128 + f] = f2bf(g - bf2f(hi));
    }
}

// ---------- stage |hrrp| into bf16 hi/lo ----------
__global__ __launch_bounds__(256) void k_stagex(
    const float* __restrict__ hrrp, unsigned short* __restrict__ xs,
    int segLen, int lgSeg, int tbase)
{
    const int m = blockIdx.x;
    const int b = m >> lgSeg, tl = m & (segLen - 1);
    const size_t bt = (size_t)b * TT + tbase + tl;
    const int col = threadIdx.x;
    if (col < 224) {
        float v = (col < 200) ? fabsf(hrrp[bt * DD + col]) : 0.f;
        unsigned short hi = f2bf(v);
        xs[(size_t)m * 448 + col] = hi;
        xs[(size_t)m * 448 + 224 + col] = f2bf(v - bf2f(hi));
    }
}

// ---------- A-fragment address for 3-term layout ----------
template<int KTOT>
__device__ __forceinline__ const unsigned short* addrA(
    const unsigned short* __restrict__ Ax, const unsigned short* __restrict__ Ag,
    int m, int ko)
{
    if (KTOT == 1056) {
        if (ko < 672) {
            int blk = ko / 224, col = ko - blk * 224;
            return Ax + (size_t)m * 448 + (blk == 2 ? 224 : 0) + col;
        }
        int kg = ko - 672, blkg = kg >> 7, colg = kg & 127;
        return Ag + (size_t)m * 256 + (blkg == 2 ? 128 : 0) + colg;
    } else {
        if (ko < 384) {
            int blk = ko >> 7, col = ko & 127;
            return Ax + (size_t)m * 256 + (blk == 2 ? 128 : 0) + col;
        }
        int kg = ko - 384, blkg = kg >> 7, colg = kg & 127;
        return Ag + (size_t)m * 256 + (blkg == 2 ? 128 : 0) + colg;
    }
}

// ---------- bf16 MFMA GEMM (+bias[n]), global_load_lds double-buffered ----------
template<int KTOT>
__global__ __launch_bounds__(256) void k_gemm(
    const unsigned short* __restrict__ Ax, const unsigned short* __restrict__ Ag,
    const unsigned short* __restrict__ Bt, const float* __restrict__ bp,
    float* __restrict__ C)
{
    __shared__ alignas(16) unsigned short Als[2][4096];
    __shared__ alignas(16) unsigned short Bls[2][4096];
    const int tid = threadIdx.x;
    const int m0 = blockIdx.x * 128, n0 = blockIdx.y * 128;
    const int wave = tid >> 6, lane = tid & 63;
    const int lm = lane & 15, lq = lane >> 4;
    const int wm = wave >> 1, wn = wave & 1;
    const int srow = tid >> 2, scol = (tid & 3) * 8;
    const int wb = wave * 512;

    const f32x4 vzero = {0.f, 0.f, 0.f, 0.f};
    f32x4 acc[4][4];
    #pragma unroll
    for (int x = 0; x < 4; ++x)
        #pragma unroll
        for (int y = 0; y < 4; ++y) acc[x][y] = vzero;

    float bn[4];
    #pragma unroll
    for (int nt = 0; nt < 4; ++nt) bn[nt] = bp[n0 + wn * 64 + nt * 16 + lm];

    constexpr int NKB = KTOT / 32;

    #define STAGE(buf, kb) do { \
        const int _ko = (kb) * 32 + scol; \
        gll16(addrA<KTOT>(Ax, Ag, m0 + srow, _ko),        &Als[buf][wb]); \
        gll16(addrA<KTOT>(Ax, Ag, m0 + 64 + srow, _ko),   &Als[buf][2048 + wb]); \
        gll16(Bt + (size_t)(n0 + srow) * KTOT + _ko,      &Bls[buf][wb]); \
        gll16(Bt + (size_t)(n0 + 64 + srow) * KTOT + _ko, &Bls[buf][2048 + wb]); \
    } while (0)

    STAGE(0, 0);
    __syncthreads();
    int cur = 0;
    for (int kb = 0; kb < NKB; ++kb) {
        if (kb + 1 < NKB) STAGE(cur ^ 1, kb + 1);
        bf16x8 af[4], bfr[4];
        #pragma unroll
        for (int mt = 0; mt < 4; ++mt)
            af[mt] = *(const bf16x8*)&Als[cur][(wm * 64 + mt * 16 + lm) * 32 + lq * 8];
        #pragma unroll
        for (int nt = 0; nt < 4; ++nt)
            bfr[nt] = *(const bf16x8*)&Bls[cur][(wn * 64 + nt * 16 + lm) * 32 + lq * 8];
        #pragma unroll
        for (int mt = 0; mt < 4; ++mt)
            #pragma unroll
            for (int nt = 0; nt < 4; ++nt)
                acc[mt][nt] = __builtin_amdgcn_mfma_f32_16x16x32_bf16(af[mt], bfr[nt], acc[mt][nt], 0, 0, 0);
        __syncthreads();
        cur ^= 1;
    }
    #undef STAGE

    #pragma unroll
    for (int mt = 0; mt < 4; ++mt) {
        #pragma unroll
        for (int nt = 0; nt < 4; ++nt) {
            const int m = m0 + wm * 64 + mt * 16 + lq * 4;
            const int n = n0 + wn * 64 + nt * 16 + lm;
            #pragma unroll
            for (int r = 0; r < 4; ++r)
                C[(size_t)(m + r) * 512 + n] = acc[mt][nt][r] + bn[nt];
        }
    }
}

// ---------- recurrent scan: 1024 thr = 4 k-quarters x 256 output-pairs ----------
// thread (kq = tid>>8, i2 = tid&255) computes partials of z[2*i2], z[2*i2+1]
// over h[kq*32 .. kq*32+32). 64 weights/thread, arch-VGPR resident
// (waves_per_eu pinned 4,4 so the allocator has the full 128-VGPR budget).
// pre already contains bias (added by k_gemm).
template<int STORE_XH, int FINAL>
__global__ __launch_bounds__(1024)
__attribute__((amdgpu_waves_per_eu(4, 4)))
void k_scan3(
    const float* __restrict__ pre, const float* __restrict__ Wh,
    float* __restrict__ st_h, float* __restrict__ st_c,
    unsigned short* __restrict__ xh, float* __restrict__ outp,
    const float* __restrict__ regw, const float* __restrict__ regb,
    int first, int R)
{
    const int tid = threadIdx.x;
    const int i2 = tid & 255;       // output pair
    const int kq = tid >> 8;        // k-quarter (wave-uniform)
    const int o1 = i2 * 2;
    const int b = blockIdx.x;
    __shared__ alignas(16) float hbuf[128];
    __shared__ alignas(16) float zbuf[4 * 512];   // [kq][o]

    // 64 weights / thread, register-resident
    float wcA[32], wcB[32];
    #pragma unroll
    for (int k = 0; k < 32; ++k) {
        const float* wp = &Wh[(size_t)(kq * 32 + k) * 512 + o1];
        wcA[k] = wp[0];
        wcB[k] = wp[1];
    }

    const float* preb = pre + (size_t)b * R * 512;
    float c = 0.f, pv0 = 0.f, pv1 = 0.f, pv2 = 0.f, pv3 = 0.f;
    if (tid < 128) {
        float h0 = 0.f;
        if (!first) { h0 = st_h[b * 128 + tid]; c = st_c[b * 128 + tid]; }
        hbuf[tid] = h0;
        pv0 = preb[tid];       pv1 = preb[128 + tid];
        pv2 = preb[256 + tid]; pv3 = preb[384 + tid];
    }
    __syncthreads();

    for (int t = 0; t < R; ++t) {
        // ---- matvec phase (all 1024 threads): 8 ds_read_b128, 64 FMA ----
        float a1 = 0.f, a2 = 0.f;
        const float* hb = &hbuf[kq * 32];
        #pragma unroll
        for (int k8 = 0; k8 < 8; ++k8) {
            const float4 h4 = *(const float4*)&hb[k8 * 4];
            a1 = fmaf(h4.x, wcA[k8 * 4 + 0], a1); a2 = fmaf(h4.x, wcB[k8 * 4 + 0], a2);
            a1 = fmaf(h4.y, wcA[k8 * 4 + 1], a1); a2 = fmaf(h4.y, wcB[k8 * 4 + 1], a2);
            a1 = fmaf(h4.z, wcA[k8 * 4 + 2], a1); a2 = fmaf(h4.z, wcB[k8 * 4 + 2], a2);
            a1 = fmaf(h4.w, wcA[k8 * 4 + 3], a1); a2 = fmaf(h4.w, wcB[k8 * 4 + 3], a2);
        }
        float2 z2; z2.x = a1; z2.y = a2;
        *(float2*)&zbuf[kq * 512 + o1] = z2;
        __syncthreads();
        // ---- gate phase (threads 0..127) ----
        if (tid < 128) {
            const float zi = zbuf[tid]
                           + zbuf[512 + tid] + zbuf[1024 + tid] + zbuf[1536 + tid] + pv0;
            const float zf = zbuf[128 + tid]
                           + zbuf[512 + 128 + tid] + zbuf[1024 + 128 + tid] + zbuf[1536 + 128 + tid] + pv1;
            const float zc = zbuf[256 + tid]
                           + zbuf[512 + 256 + tid] + zbuf[1024 + 256 + tid] + zbuf[1536 + 256 + tid] + pv2;
            const float zo = zbuf[384 + tid]
                           + zbuf[512 + 384 + tid] + zbuf[1024 + 384 + tid] + zbuf[1536 + 384 + tid] + pv3;
            const float ig = sigm(zi);
            const float fg = sigm(zf);
            const float ch = tanh_(zc);
            const float og = sigm(zo);
            c = fg * c + ig * ch;
            const float h2 = og * tanh_(c);
            hbuf[tid] = h2;
            if (STORE_XH) {
                unsigned short hi = f2bf(h2);
                size_t row = (size_t)b * R + t;
                xh[row * 256 + tid] = hi;
                xh[row * 256 + 128 + tid] = f2bf(h2 - bf2f(hi));
            }
            // prefetch next step's pre (hides under the next matvec)
            if (t + 1 < R) {
                const float* pnx = preb + (size_t)(t + 1) * 512;
                pv0 = pnx[tid];       pv1 = pnx[128 + tid];
                pv2 = pnx[256 + tid]; pv3 = pnx[384 + tid];
            }
        }
        __syncthreads();
    }
    if (tid < 128) { st_h[b * 128 + tid] = hbuf[tid]; st_c[b * 128 + tid] = c; }
    if (FINAL && tid < 2) {
        float s = regb[tid];
        #pragma unroll 4
        for (int i = 0; i < 128; ++i) s = fmaf(hbuf[i], regw[i * 2 + tid], s);
        outp[b * 2 + tid] = s;   // f32 output
    }
}

// ---------- host ----------
extern "C" void kernel_launch(void* const* d_in, const int* in_sizes, int n_in,
                              void* d_out, int out_size, void* d_ws, size_t ws_size,
                              hipStream_t stream)
{
    const float* hrrp = (const float*)d_in[0];
    const float* ac   = (const float*)d_in[1];
    const float* pc   = (const float*)d_in[2];
    const float* rd   = (const float*)d_in[3];
    const float* w_amp= (const float*)d_in[4];
    const float* b_amp= (const float*)d_in[5];
    const float* w_ph = (const float*)d_in[6];
    const float* b_ph = (const float*)d_in[7];
    const float* w_g  = (const float*)d_in[8];
    const float* b_g  = (const float*)d_in[9];
    const float* w_r1 = (const float*)d_in[10];
    const float* b_r1 = (const float*)d_in[11];
    const float* w_r2 = (const float*)d_in[12];
    const float* b_r2 = (const float*)d_in[13];
    const float* w_q  = (const float*)d_in[14];
    const float* b_q  = (const float*)d_in[15];
    const float* w_k  = (const float*)d_in[16];
    const float* b_k  = (const float*)d_in[17];
    const float* w_v  = (const float*)d_in[18];
    const float* b_v  = (const float*)d_in[19];
    const float* w_o  = (const float*)d_in[20];
    const float* b_o  = (const float*)d_in[21];
    const float* w0   = (const float*)d_in[22];
    const float* b0   = (const float*)d_in[23];
    const float* gw0  = (const float*)d_in[24];
    const float* w12  = (const float*)d_in[25];
    const float* b12  = (const float*)d_in[26];
    const float* gw12 = (const float*)d_in[27];
    const float* regw = (const float*)d_in[28];
    const float* regb = (const float*)d_in[29];
    float* outp = (float*)d_out;

    const size_t need64 = 68452352ULL, need32 = 35946496ULL;
    const size_t EXTRA = 132864ULL;     // GT + WVO + e1 + e2 + bvo + e0
    int R, lg, folded;
    if      (ws_size >= need64 + EXTRA) { R = 64; lg = 6; folded = 1; }
    else if (ws_size >= need64)         { R = 64; lg = 6; folded = 0; }
    else if (ws_size >= need32 + EXTRA) { R = 32; lg = 5; folded = 1; }
    else if (ws_size >= need32)         { R = 32; lg = 5; folded = 0; }
    else return;
    const int NSEG = TT / R;
    const int MR = BB * R;

    char* ws = (char*)d_ws;
    size_t off = 0;
    float* pre = (float*)(ws + off);                   off += (size_t)MR * 512 * 4;
    unsigned short* gsh = (unsigned short*)(ws + off); off += (size_t)MR * 256 * 2;
    unsigned short* xh  = (unsigned short*)(ws + off); off += (size_t)MR * 256 * 2;
    unsigned short* xs  = (unsigned short*)(ws + off); off += (size_t)MR * 448 * 2;
    float* sh0 = (float*)(ws + off); off += 131072;
    float* sc0 = (float*)(ws + off); off += 131072;
    float* sh1 = (float*)(ws + off); off += 131072;
    float* sc1 = (float*)(ws + off); off += 131072;
    float* sh2 = (float*)(ws + off); off += 131072;
    float* sc2 = (float*)(ws + off); off += 131072;
    unsigned short* b0t = (unsigned short*)(ws + off); off += 512 * 1056 * 2;
    unsigned short* b1t = (unsigned short*)(ws + off); off += 512 * 768 * 2;
    unsigned short* b2t = (unsigned short*)(ws + off); off += 512 * 768 * 2;
    float* GT = nullptr; float* WVO = nullptr;
    float* e1p = nullptr; float* e2p = nullptr; float* bvop = nullptr; float* e0p = nullptr;
    if (folded) {
        GT   = (float*)(ws + off); off += 128 * 128 * 4;
        WVO  = (float*)(ws + off); off += 128 * 128 * 4;
        e1p  = (float*)(ws + off); off += 512;
        e2p  = (float*)(ws + off); off += 512;
        bvop = (float*)(ws + off); off += 512;
        e0p  = (float*)(ws + off); off += 256;
    }

    k_prep_b<<<512, 256, 0, stream>>>(w0, gw0, w12, gw12, b0t, b1t, b2t);
    if (folded)
        k_prep_fuse<<<128, 128, 0, stream>>>(w_q, b_q, w_k, b_k, w_v, b_v, w_o,
                                             GT, WVO, e1p, e2p, e0p, bvop);

    for (int seg = 0; seg < NSEG; ++seg) {
        const int first = (seg == 0) ? 1 : 0;
        const int tbase = seg * R;
        if (folded)
            k_gamma2<<<MR / 16, 256, 0, stream>>>(ac, pc, rd, w_amp, b_amp, w_ph, b_ph,
                                                  w_g, b_g, w_r1, b_r1, w_r2, b_r2,
                                                  GT, WVO, e1p, e2p, e0p, bvop, b_o,
                                                  gsh, R, lg, tbase);
        else
            k_gamma<<<MR / 16, 128, 0, stream>>>(ac, pc, rd, w_amp, b_amp, w_ph, b_ph,
                                                 w_g, b_g, w_r1, b_r1, w_r2, b_r2,
                                                 w_q, b_q, w_k, b_k, w_v, b_v, w_o, b_o,
                                                 gsh, R, lg, tbase);
        k_stagex<<<MR, 256, 0, stream>>>(hrrp, xs, R, lg, tbase);
        // layer 0
        k_gemm<1056><<<dim3(MR / 128, 4), 256, 0, stream>>>(xs, gsh, b0t, b0, pre);
        k_scan3<1, 0><<<BB, 1024, 0, stream>>>(pre, w0, sh0, sc0, xh,
                                               nullptr, nullptr, nullptr, first, R);
        // layer 1
        k_gemm<768><<<dim3(MR / 128, 4), 256, 0, stream>>>(xh, gsh, b1t, b12, pre);
        k_scan3<1, 0><<<BB, 1024, 0, stream>>>(pre, w12, sh1, sc1, xh,
                                               nullptr, nullptr, nullptr, first, R);
        // layer 2
        k_gemm<768><<<dim3(MR / 128, 4), 256, 0, stream>>>(xh, gsh, b2t, b12 + 512, pre);
        if (seg < NSEG - 1)
            k_scan3<0, 0><<<BB, 1024, 0, stream>>>(pre, w12 + 256 * 512, sh2, sc2,
                                                   nullptr, nullptr, nullptr, nullptr, first, R);
        else
            k_scan3<0, 1><<<BB, 1024, 0, stream>>>(pre, w12 + 256 * 512, sh2, sc2,
                                                   nullptr, outp, regw, regb, first, R);
    }
}

// Round 6
// 2685.481 us; speedup vs baseline: 2.0455x; 1.0253x over previous
//
#include <hip/hip_runtime.h>

#define BB 256
#define TT 512
#define DD 200

// ---------- helpers ----------
__device__ __forceinline__ float bf2f(unsigned short u) {
    return __uint_as_float(((unsigned int)u) << 16);
}
__device__ __forceinline__ unsigned short f2bf(float f) {
    unsigned int u = __float_as_uint(f);
    u += 0x7FFFu + ((u >> 16) & 1u);
    return (unsigned short)(u >> 16);
}
__device__ __forceinline__ float sigm(float x) { return 1.0f / (1.0f + __expf(-x)); }
__device__ __forceinline__ float tanh_(float x) { return 1.0f - 2.0f / (__expf(2.0f * x) + 1.0f); }

typedef __bf16 bf16x8 __attribute__((ext_vector_type(8)));
typedef float  f32x4  __attribute__((ext_vector_type(4)));

#define GPAD 20

// async global->LDS 16B (dest = wave-uniform base + lane*16)
__device__ __forceinline__ void gll16(const unsigned short* g, unsigned short* l) {
    __builtin_amdgcn_global_load_lds(
        (const __attribute__((address_space(1))) unsigned int*)g,
        (__attribute__((address_space(3))) unsigned int*)l,
        16, 0, 0);
}

#define MAC16(ACCV, BASE, W) do { \
    const float4* _p4 = (const float4*)(BASE); \
    float4 _v0 = _p4[0], _v1 = _p4[1], _v2 = _p4[2], _v3 = _p4[3]; \
    ACCV[0]  = fmaf(_v0.x,(W),ACCV[0]);  ACCV[1]  = fmaf(_v0.y,(W),ACCV[1]); \
    ACCV[2]  = fmaf(_v0.z,(W),ACCV[2]);  ACCV[3]  = fmaf(_v0.w,(W),ACCV[3]); \
    ACCV[4]  = fmaf(_v1.x,(W),ACCV[4]);  ACCV[5]  = fmaf(_v1.y,(W),ACCV[5]); \
    ACCV[6]  = fmaf(_v1.z,(W),ACCV[6]);  ACCV[7]  = fmaf(_v1.w,(W),ACCV[7]); \
    ACCV[8]  = fmaf(_v2.x,(W),ACCV[8]);  ACCV[9]  = fmaf(_v2.y,(W),ACCV[9]); \
    ACCV[10] = fmaf(_v2.z,(W),ACCV[10]); ACCV[11] = fmaf(_v2.w,(W),ACCV[11]); \
    ACCV[12] = fmaf(_v3.x,(W),ACCV[12]); ACCV[13] = fmaf(_v3.y,(W),ACCV[13]); \
    ACCV[14] = fmaf(_v3.z,(W),ACCV[14]); ACCV[15] = fmaf(_v3.w,(W),ACCV[15]); \
} while (0)

#define MAC8(ACCV, BASE, W) do { \
    const float4* _p4 = (const float4*)(BASE); \
    float4 _v0 = _p4[0], _v1 = _p4[1]; \
    ACCV[0] = fmaf(_v0.x,(W),ACCV[0]); ACCV[1] = fmaf(_v0.y,(W),ACCV[1]); \
    ACCV[2] = fmaf(_v0.z,(W),ACCV[2]); ACCV[3] = fmaf(_v0.w,(W),ACCV[3]); \
    ACCV[4] = fmaf(_v1.x,(W),ACCV[4]); ACCV[5] = fmaf(_v1.y,(W),ACCV[5]); \
    ACCV[6] = fmaf(_v1.z,(W),ACCV[6]); ACCV[7] = fmaf(_v1.w,(W),ACCV[7]); \
} while (0)

#define MAC8_2(A1, A2, BASE, W1, W2) do { \
    const float4* _p4 = (const float4*)(BASE); \
    float4 _v0 = _p4[0], _v1 = _p4[1]; \
    A1[0] = fmaf(_v0.x,(W1),A1[0]); A2[0] = fmaf(_v0.x,(W2),A2[0]); \
    A1[1] = fmaf(_v0.y,(W1),A1[1]); A2[1] = fmaf(_v0.y,(W2),A2[1]); \
    A1[2] = fmaf(_v0.z,(W1),A1[2]); A2[2] = fmaf(_v0.z,(W2),A2[2]); \
    A1[3] = fmaf(_v0.w,(W1),A1[3]); A2[3] = fmaf(_v0.w,(W2),A2[3]); \
    A1[4] = fmaf(_v1.x,(W1),A1[4]); A2[4] = fmaf(_v1.x,(W2),A2[4]); \
    A1[5] = fmaf(_v1.y,(W1),A1[5]); A2[5] = fmaf(_v1.y,(W2),A2[5]); \
    A1[6] = fmaf(_v1.z,(W1),A1[6]); A2[6] = fmaf(_v1.z,(W2),A2[6]); \
    A1[7] = fmaf(_v1.w,(W1),A1[7]); A2[7] = fmaf(_v1.w,(W2),A2[7]); \
} while (0)

// ---------- build B matrices (bf16 hi/lo 3-term layout) from f32 weights ----------
__global__ __launch_bounds__(256) void k_prep_b(
    const float* __restrict__ w0, const float* __restrict__ gw0,
    const float* __restrict__ w12, const float* __restrict__ gw12,
    unsigned short* __restrict__ b0t, unsigned short* __restrict__ b1t,
    unsigned short* __restrict__ b2t)
{
    const int n = blockIdx.x;
    const int gate = n >> 7, oo = n & 127;
    const float sgn = (gate == 1) ? -0.5f : 1.0f;
    for (int k = threadIdx.x; k < 1056; k += 256) {
        float w; int isLo;
        if (k < 672) {
            int blk = k / 224, col = k - blk * 224;
            w = (col < 200) ? w0[(size_t)(128 + col) * 512 + n] : 0.f;
            isLo = (blk == 1);
        } else {
            int kg = k - 672, blkg = kg >> 7, colg = kg & 127;
            w = sgn * gw0[(size_t)(gate * 128 + colg) * 128 + oo];
            isLo = (blkg == 1);
        }
        unsigned short hi = f2bf(w);
        b0t[(size_t)n * 1056 + k] = isLo ? f2bf(w - bf2f(hi)) : hi;
    }
    for (int l = 0; l < 2; ++l) {
        unsigned short* dst = l ? b2t : b1t;
        for (int k = threadIdx.x; k < 768; k += 256) {
            float w; int isLo;
            if (k < 384) {
                int blk = k >> 7, col = k & 127;
                w = w12[(size_t)(l * 256 + 128 + col) * 512 + n];
                isLo = (blk == 1);
            } else {
                int kg = k - 384, blkg = kg >> 7, colg = kg & 127;
                w = sgn * gw12[(size_t)((l * 4 + gate) * 128 + colg) * 128 + oo];
                isLo = (blkg == 1);
            }
            unsigned short hi = f2bf(w);
            dst[(size_t)n * 768 + k] = isLo ? f2bf(w - bf2f(hi)) : hi;
        }
    }
}

// ---------- one-time fusion-weight folding ----------
__global__ __launch_bounds__(128) void k_prep_fuse(
    const float* __restrict__ w_q, const float* __restrict__ b_q,
    const float* __restrict__ w_k, const float* __restrict__ b_k,
    const float* __restrict__ w_v, const float* __restrict__ b_v,
    const float* __restrict__ w_o,
    float* __restrict__ GT, float* __restrict__ WVO,
    float* __restrict__ e1, float* __restrict__ e2,
    float* __restrict__ e0, float* __restrict__ bvo)
{
    __shared__ float sk[128], sv[128];
    __shared__ float rtmp[8];
    const int i = blockIdx.x, f = threadIdx.x;
    sk[f] = w_k[(size_t)i * 128 + f];
    sv[f] = w_v[(size_t)i * 128 + f];
    __syncthreads();
    float g = 0.f, wv = 0.f;
    #pragma unroll 4
    for (int a = 0; a < 128; ++a) {
        g  = fmaf(w_q[(size_t)f * 128 + a], sk[a], g);
        wv = fmaf(sv[a], w_o[(size_t)a * 128 + f], wv);
    }
    GT[(size_t)i * 128 + f] = g;
    WVO[(size_t)i * 128 + f] = wv;
    float p1 = w_q[(size_t)i * 128 + f] * b_k[f];
    float p2 = sk[f] * b_q[f];
    #pragma unroll
    for (int sh = 32; sh > 0; sh >>= 1) {
        p1 += __shfl_xor(p1, sh, 64);
        p2 += __shfl_xor(p2, sh, 64);
    }
    if ((f & 63) == 0) { rtmp[(f >> 6) * 2] = p1; rtmp[(f >> 6) * 2 + 1] = p2; }
    __syncthreads();
    if (f == 0) { e1[i] = rtmp[0] + rtmp[2]; e2[i] = rtmp[1] + rtmp[3]; }
    if (i == 0) {
        float bw = 0.f;
        #pragma unroll 4
        for (int a = 0; a < 128; ++a) bw = fmaf(b_v[a], w_o[(size_t)a * 128 + f], bw);
        bvo[f] = bw;
        float p0 = b_q[f] * b_k[f];
        #pragma unroll
        for (int sh = 32; sh > 0; sh >>= 1) p0 += __shfl_xor(p0, sh, 64);
        if ((f & 63) == 0) rtmp[4 + (f >> 6)] = p0;
        __syncthreads();
        if (f == 0) e0[0] = rtmp[4] + rtmp[5];
    }
}

// ---------- folded TwoStageFusion, 256 threads (2 token-halves x 128 f) ----------
__global__ __launch_bounds__(256, 4) void k_gamma2(
    const float* __restrict__ ac, const float* __restrict__ pc,
    const float* __restrict__ rd,
    const float* __restrict__ w_amp, const float* __restrict__ b_amp,
    const float* __restrict__ w_ph,  const float* __restrict__ b_ph,
    const float* __restrict__ w_g,   const float* __restrict__ b_g,
    const float* __restrict__ w_r1,  const float* __restrict__ b_r1,
    const float* __restrict__ w_r2,  const float* __restrict__ b_r2,
    const float* __restrict__ GT,    const float* __restrict__ WVO,
    const float* __restrict__ e1,    const float* __restrict__ e2,
    const float* __restrict__ e0,    const float* __restrict__ bvo,
    const float* __restrict__ b_o,
    unsigned short* __restrict__ gsh, int segLen, int lgSeg, int tbase)
{
    __shared__ alignas(16) float catT[256][GPAD];
    __shared__ alignas(16) float rlT[128][GPAD];
    __shared__ float scin[4][16];
    __shared__ float red[2][2][8];

    const int tid = threadIdx.x;
    const int f = tid & 127;
    const int th = tid >> 7;        // token half
    const int t0 = th * 8;
    const int r0 = blockIdx.x * 16;
    const int b = r0 >> lgSeg;
    const int tl = r0 & (segLen - 1);
    const int tau0 = tbase + tl - 1;

    if (tid < 64) {
        int j = tid >> 4, tt = tid & 15;
        int tau = tau0 + tt; if (tau < 0) tau = 0;
        size_t tok = (size_t)b * TT + tau;
        float v;
        if (j == 0) v = ac[tok];
        else if (j == 1) v = pc[tok];
        else v = rd[tok * 2 + (j - 2)];
        scin[j][tt] = v;
    }
    const float wa = w_amp[f], ba = b_amp[f];
    const float wp = w_ph[f],  bpv = b_ph[f];
    const float w1a = w_r1[f], w1b = w_r1[128 + f];
    const float br1 = b_r1[f], br2v = b_r2[f];
    const float bg = b_g[f];
    __syncthreads();

    float ph8[8], am8[8];
    #pragma unroll
    for (int t = 0; t < 8; ++t) {
        float a = scin[0][t0 + t], p = scin[1][t0 + t];
        float r0v = scin[2][t0 + t], r1v = scin[3][t0 + t];
        float phv = tanh_(fmaf(p, wp, bpv));
        float amv = tanh_(fmaf(a, wa, ba));
        ph8[t] = phv; am8[t] = amv;
        catT[f][t0 + t] = phv;
        catT[128 + f][t0 + t] = amv;
        rlT[f][t0 + t] = tanh_(fmaf(r1v, w1b, fmaf(r0v, w1a, br1)));
    }
    __syncthreads();

    // pass 1: gate logits (K=256) + rlos layer2 (K=128)
    float bacc[8], racc[8];
    #pragma unroll
    for (int t = 0; t < 8; ++t) { bacc[t] = 0.f; racc[t] = 0.f; }
    #pragma unroll 2
    for (int i = 0; i < 128; ++i) {
        float wg1 = w_g[i * 128 + f];
        float wg2 = w_g[(128 + i) * 128 + f];
        float wr  = w_r2[i * 128 + f];
        MAC8(bacc, &catT[i][t0], wg1);
        MAC8(bacc, &catT[128 + i][t0], wg2);
        MAC8(racc, &rlT[i][t0], wr);
    }
    float corr8[8], rl8[8];
    #pragma unroll
    for (int t = 0; t < 8; ++t) {
        float beta = sigm(bacc[t] + bg);
        corr8[t] = fmaf(beta, ph8[t] - am8[t], am8[t]);
        rl8[t] = tanh_(racc[t] + br2v);
    }
    __syncthreads();
    #pragma unroll
    for (int t = 0; t < 8; ++t) rlT[f][t0 + t] = rl8[t];
    __syncthreads();

    // pass 2 (dual): u = G.rl  and  vo = rl.(WvWo)
    float uacc[8], voacc[8];
    #pragma unroll
    for (int t = 0; t < 8; ++t) { uacc[t] = 0.f; voacc[t] = 0.f; }
    #pragma unroll 2
    for (int i = 0; i < 128; ++i) {
        float wu = GT[i * 128 + f];
        float wv = WVO[i * 128 + f];
        MAC8_2(uacc, voacc, &rlT[i][t0], wu, wv);
    }

    const int lane = tid & 63, wv2 = (tid >> 6) & 1;
    const float e1f = e1[f], e2f = e2[f], e0v = e0[0];
    #pragma unroll
    for (int t = 0; t < 8; ++t) {
        float pdot = fmaf(corr8[t], uacc[t] + e1f, rl8[t] * e2f);
        #pragma unroll
        for (int sh = 32; sh > 0; sh >>= 1) pdot += __shfl_xor(pdot, sh, 64);
        if (lane == 0) red[th][wv2][t] = pdot;
    }
    __syncthreads();
    const float bvof = bvo[f], bof = b_o[f];
    #pragma unroll
    for (int t = 0; t < 8; ++t) {
        float attn = sigm((red[th][0][t] + red[th][1][t] + e0v) * 0.088388347648318447f);
        float g = fmaf(attn, voacc[t] + bvof, bof);
        if (tau0 + t0 + t < 0) g = 0.f;
        unsigned short hi = f2bf(g);
        gsh[(size_t)(r0 + t0 + t) * 256 + f] = hi;
        gsh[(size_t)(r0 + t0 + t) * 256 + 128 + f] = f2bf(g - bf2f(hi));
    }
}

// ---------- legacy (un-folded) fusion kernel: fallback if workspace is tight ----------
__global__ __launch_bounds__(128) void k_gamma(
    const float* __restrict__ ac, const float* __restrict__ pc,
    const float* __restrict__ rd,
    const float* __restrict__ w_amp, const float* __restrict__ b_amp,
    const float* __restrict__ w_ph,  const float* __restrict__ b_ph,
    const float* __restrict__ w_g,   const float* __restrict__ b_g,
    const float* __restrict__ w_r1,  const float* __restrict__ b_r1,
    const float* __restrict__ w_r2,  const float* __restrict__ b_r2,
    const float* __restrict__ w_q,   const float* __restrict__ b_q,
    const float* __restrict__ w_k,   const float* __restrict__ b_k,
    const float* __restrict__ w_v,   const float* __restrict__ b_v,
    const float* __restrict__ w_o,   const float* __restrict__ b_o,
    unsigned short* __restrict__ gsh, int segLen, int lgSeg, int tbase)
{
    __shared__ alignas(16) float catT[256][GPAD];
    __shared__ alignas(16) float rlT[128][GPAD];
    __shared__ alignas(16) float avT[128][GPAD];
    __shared__ float scin[4][16];
    __shared__ float red[2][16];

    const int f = threadIdx.x;
    const int r0 = blockIdx.x * 16;
    const int b = r0 >> lgSeg;
    const int tl = r0 & (segLen - 1);
    const int tau0 = tbase + tl - 1;

    if (f < 64) {
        int j = f >> 4, tt = f & 15;
        int tau = tau0 + tt; if (tau < 0) tau = 0;
        size_t tok = (size_t)b * TT + tau;
        float v;
        if (j == 0) v = ac[tok];
        else if (j == 1) v = pc[tok];
        else v = rd[tok * 2 + (j - 2)];
        scin[j][tt] = v;
    }
    const float wa = w_amp[f], ba = b_amp[f];
    const float wp = w_ph[f],  bpv = b_ph[f];
    const float w1a = w_r1[f], w1b = w_r1[128 + f];
    const float br1 = b_r1[f], br2 = b_r2[f];
    const float bg = b_g[f];
    const float bqv = b_q[f], bkv = b_k[f];
    const float bvv = b_v[f], bov = b_o[f];
    __syncthreads();

    float ph16[16], am16[16];
    #pragma unroll
    for (int t = 0; t < 16; ++t) {
        float a = scin[0][t], p = scin[1][t], r0v = scin[2][t], r1v = scin[3][t];
        float phv = tanh_(fmaf(p, wp, bpv));
        float amv = tanh_(fmaf(a, wa, ba));
        ph16[t] = phv; am16[t] = amv;
        catT[f][t] = phv;
        catT[128 + f][t] = amv;
        rlT[f][t] = tanh_(fmaf(r1v, w1b, fmaf(r0v, w1a, br1)));
    }
    __syncthreads();

    float bacc[16], racc[16];
    #pragma unroll
    for (int t = 0; t < 16; ++t) { bacc[t] = 0.f; racc[t] = 0.f; }
    #pragma unroll 2
    for (int i = 0; i < 128; ++i) {
        float wg1 = w_g[i * 128 + f];
        float wg2 = w_g[(128 + i) * 128 + f];
        float wr  = w_r2[i * 128 + f];
        MAC16(bacc, &catT[i][0], wg1);
        MAC16(bacc, &catT[128 + i][0], wg2);
        MAC16(racc, &rlT[i][0], wr);
    }
    float corr16[16], rl16[16];
    #pragma unroll
    for (int t = 0; t < 16; ++t) {
        float beta = sigm(bacc[t] + bg);
        corr16[t] = fmaf(beta, ph16[t] - am16[t], am16[t]);
        rl16[t] = tanh_(racc[t] + br2);
    }
    __syncthreads();
    #pragma unroll
    for (int t = 0; t < 16; ++t) { catT[f][t] = corr16[t]; rlT[f][t] = rl16[t]; }
    __syncthreads();

    float qa[16], ka[16], va[16];
    #pragma unroll
    for (int t = 0; t < 16; ++t) { qa[t] = 0.f; ka[t] = 0.f; va[t] = 0.f; }
    #pragma unroll 2
    for (int i = 0; i < 128; ++i) {
        float wq = w_q[i * 128 + f];
        float wk = w_k[i * 128 + f];
        float wv = w_v[i * 128 + f];
        MAC16(qa, &catT[i][0], wq);
        MAC16(ka, &rlT[i][0], wk);
        MAC16(va, &rlT[i][0], wv);
    }
    const int lane = f & 63, wvi = f >> 6;
    #pragma unroll
    for (int t = 0; t < 16; ++t) {
        float pdot = (qa[t] + bqv) * (ka[t] + bkv);
        #pragma unroll
        for (int sh = 32; sh > 0; sh >>= 1) pdot += __shfl_xor(pdot, sh, 64);
        if (lane == 0) red[wvi][t] = pdot;
    }
    __syncthreads();
    #pragma unroll
    for (int t = 0; t < 16; ++t) {
        float attn = sigm((red[0][t] + red[1][t]) * 0.088388347648318447f);
        avT[f][t] = attn * (va[t] + bvv);
    }
    __syncthreads();
    float oacc[16];
    #pragma unroll
    for (int t = 0; t < 16; ++t) oacc[t] = 0.f;
    #pragma unroll 2
    for (int i = 0; i < 128; ++i) {
        float wo = w_o[i * 128 + f];
        MAC16(oacc, &avT[i][0], wo);
    }
    #pragma unroll
    for (int t = 0; t < 16; ++t) {
        float g = oacc[t] + bov;
        if (tau0 + t < 0) g = 0.f;
        unsigned short hi = f2bf(g);
        gsh[(size_t)(r0 + t) * 256 + f] = hi;
        gsh[(size_t)(r0 + t) * 256 + 128 + f] = f2bf(g - bf2f(hi));
    }
}

// ---------- stage |hrrp| into bf16 hi/lo ----------
__global__ __launch_bounds__(256) void k_stagex(
    const float* __restrict__ hrrp, unsigned short* __restrict__ xs,
    int segLen, int lgSeg, int tbase)
{
    const int m = blockIdx.x;
    const int b = m >> lgSeg, tl = m & (segLen - 1);
    const size_t bt = (size_t)b * TT + tbase + tl;
    const int col = threadIdx.x;
    if (col < 224) {
        float v = (col < 200) ? fabsf(hrrp[bt * DD + col]) : 0.f;
        unsigned short hi = f2bf(v);
        xs[(size_t)m * 448 + col] = hi;
        xs[(size_t)m * 448 + 224 + col] = f2bf(v - bf2f(hi));
    }
}

// ---------- A-fragment address for 3-term layout ----------
template<int KTOT>
__device__ __forceinline__ const unsigned short* addrA(
    const unsigned short* __restrict__ Ax, const unsigned short* __restrict__ Ag,
    int m, int ko)
{
    if (KTOT == 1056) {
        if (ko < 672) {
            int blk = ko / 224, col = ko - blk * 224;
            return Ax + (size_t)m * 448 + (blk == 2 ? 224 : 0) + col;
        }
        int kg = ko - 672, blkg = kg >> 7, colg = kg & 127;
        return Ag + (size_t)m * 256 + (blkg == 2 ? 128 : 0) + colg;
    } else {
        if (ko < 384) {
            int blk = ko >> 7, col = ko & 127;
            return Ax + (size_t)m * 256 + (blk == 2 ? 128 : 0) + col;
        }
        int kg = ko - 384, blkg = kg >> 7, colg = kg & 127;
        return Ag + (size_t)m * 256 + (blkg == 2 ? 128 : 0) + colg;
    }
}

// ---------- bf16 MFMA GEMM (+bias[n]), global_load_lds double-buffered ----------
template<int KTOT>
__global__ __launch_bounds__(256) void k_gemm(
    const unsigned short* __restrict__ Ax, const unsigned short* __restrict__ Ag,
    const unsigned short* __restrict__ Bt, const float* __restrict__ bp,
    float* __restrict__ C)
{
    __shared__ alignas(16) unsigned short Als[2][4096];
    __shared__ alignas(16) unsigned short Bls[2][4096];
    const int tid = threadIdx.x;
    const int m0 = blockIdx.x * 128, n0 = blockIdx.y * 128;
    const int wave = tid >> 6, lane = tid & 63;
    const int lm = lane & 15, lq = lane >> 4;
    const int wm = wave >> 1, wn = wave & 1;
    const int srow = tid >> 2, scol = (tid & 3) * 8;
    const int wb = wave * 512;

    const f32x4 vzero = {0.f, 0.f, 0.f, 0.f};
    f32x4 acc[4][4];
    #pragma unroll
    for (int x = 0; x < 4; ++x)
        #pragma unroll
        for (int y = 0; y < 4; ++y) acc[x][y] = vzero;

    float bn[4];
    #pragma unroll
    for (int nt = 0; nt < 4; ++nt) bn[nt] = bp[n0 + wn * 64 + nt * 16 + lm];

    constexpr int NKB = KTOT / 32;

    #define STAGE(buf, kb) do { \
        const int _ko = (kb) * 32 + scol; \
        gll16(addrA<KTOT>(Ax, Ag, m0 + srow, _ko),        &Als[buf][wb]); \
        gll16(addrA<KTOT>(Ax, Ag, m0 + 64 + srow, _ko),   &Als[buf][2048 + wb]); \
        gll16(Bt + (size_t)(n0 + srow) * KTOT + _ko,      &Bls[buf][wb]); \
        gll16(Bt + (size_t)(n0 + 64 + srow) * KTOT + _ko, &Bls[buf][2048 + wb]); \
    } while (0)

    STAGE(0, 0);
    __syncthreads();
    int cur = 0;
    for (int kb = 0; kb < NKB; ++kb) {
        if (kb + 1 < NKB) STAGE(cur ^ 1, kb + 1);
        bf16x8 af[4], bfr[4];
        #pragma unroll
        for (int mt = 0; mt < 4; ++mt)
            af[mt] = *(const bf16x8*)&Als[cur][(wm * 64 + mt * 16 + lm) * 32 + lq * 8];
        #pragma unroll
        for (int nt = 0; nt < 4; ++nt)
            bfr[nt] = *(const bf16x8*)&Bls[cur][(wn * 64 + nt * 16 + lm) * 32 + lq * 8];
        #pragma unroll
        for (int mt = 0; mt < 4; ++mt)
            #pragma unroll
            for (int nt = 0; nt < 4; ++nt)
                acc[mt][nt] = __builtin_amdgcn_mfma_f32_16x16x32_bf16(af[mt], bfr[nt], acc[mt][nt], 0, 0, 0);
        __syncthreads();
        cur ^= 1;
    }
    #undef STAGE

    #pragma unroll
    for (int mt = 0; mt < 4; ++mt) {
        #pragma unroll
        for (int nt = 0; nt < 4; ++nt) {
            const int m = m0 + wm * 64 + mt * 16 + lq * 4;
            const int n = n0 + wn * 64 + nt * 16 + lm;
            #pragma unroll
            for (int r = 0; r < 4; ++r)
                C[(size_t)(m + r) * 512 + n] = acc[mt][nt][r] + bn[nt];
        }
    }
}

// ---------- recurrent scan v4: 3-phase step with parallel activations ----------
// matvec: 1024 thr = 4 k-quarters x 256 output-pairs (64 w/thread, reg-resident)
// phase A: 512 thr, one gate-output each: 4-partial sum + pv -> activation -> actb
// phase B: 128 thr: combine 4 activations, c/h update, hi/lo store
template<int STORE_XH, int FINAL>
__global__ __launch_bounds__(1024)
__attribute__((amdgpu_waves_per_eu(4, 4)))
void k_scan4(
    const float* __restrict__ pre, const float* __restrict__ Wh,
    float* __restrict__ st_h, float* __restrict__ st_c,
    unsigned short* __restrict__ xh, float* __restrict__ outp,
    const float* __restrict__ regw, const float* __restrict__ regb,
    int first, int R)
{
    const int tid = threadIdx.x;
    const int i2 = tid & 255;       // output pair
    const int kq = tid >> 8;        // k-quarter (wave-group uniform)
    const int o1 = i2 * 2;
    const int b = blockIdx.x;
    __shared__ alignas(16) float hbuf[128];
    __shared__ alignas(16) float zbuf[4 * 512];   // [kq][o]
    __shared__ float actb[4 * 132];               // [gate][channel], pad 132

    // 64 weights / thread, register-resident
    float wcA[32], wcB[32];
    #pragma unroll
    for (int k = 0; k < 32; ++k) {
        const float* wp = &Wh[(size_t)(kq * 32 + k) * 512 + o1];
        wcA[k] = wp[0];
        wcB[k] = wp[1];
    }

    const float* preb = pre + (size_t)b * R * 512;
    float c = 0.f;
    float pv = 0.f;
    if (tid < 512) pv = preb[tid];          // one gate-output per thread
    if (tid < 128) {
        float h0 = 0.f;
        if (!first) { h0 = st_h[b * 128 + tid]; c = st_c[b * 128 + tid]; }
        hbuf[tid] = h0;
    }
    __syncthreads();

    for (int t = 0; t < R; ++t) {
        // ---- matvec phase (all 1024 threads): 8 broadcast b128 reads, 64 FMA ----
        float a1 = 0.f, a2 = 0.f, c1 = 0.f, c2 = 0.f;
        const float* hb = &hbuf[kq * 32];
        #pragma unroll
        for (int k8 = 0; k8 < 4; ++k8) {
            const float4 h4 = *(const float4*)&hb[k8 * 4];
            const float4 h5 = *(const float4*)&hb[16 + k8 * 4];
            a1 = fmaf(h4.x, wcA[k8 * 4 + 0], a1); a2 = fmaf(h4.x, wcB[k8 * 4 + 0], a2);
            c1 = fmaf(h5.x, wcA[16 + k8 * 4 + 0], c1); c2 = fmaf(h5.x, wcB[16 + k8 * 4 + 0], c2);
            a1 = fmaf(h4.y, wcA[k8 * 4 + 1], a1); a2 = fmaf(h4.y, wcB[k8 * 4 + 1], a2);
            c1 = fmaf(h5.y, wcA[16 + k8 * 4 + 1], c1); c2 = fmaf(h5.y, wcB[16 + k8 * 4 + 1], c2);
            a1 = fmaf(h4.z, wcA[k8 * 4 + 2], a1); a2 = fmaf(h4.z, wcB[k8 * 4 + 2], a2);
            c1 = fmaf(h5.z, wcA[16 + k8 * 4 + 2], c1); c2 = fmaf(h5.z, wcB[16 + k8 * 4 + 2], c2);
            a1 = fmaf(h4.w, wcA[k8 * 4 + 3], a1); a2 = fmaf(h4.w, wcB[k8 * 4 + 3], a2);
            c1 = fmaf(h5.w, wcA[16 + k8 * 4 + 3], c1); c2 = fmaf(h5.w, wcB[16 + k8 * 4 + 3], c2);
        }
        float2 z2; z2.x = a1 + c1; z2.y = a2 + c2;
        *(float2*)&zbuf[kq * 512 + o1] = z2;
        __syncthreads();
        // ---- phase A (threads 0..511): one activation each ----
        if (tid < 512) {
            const float zs = zbuf[tid] + zbuf[512 + tid] + zbuf[1024 + tid]
                           + zbuf[1536 + tid] + pv;
            const int g = tid >> 7, j = tid & 127;
            actb[g * 132 + j] = (g == 2) ? tanh_(zs) : sigm(zs);
            if (t + 1 < R) pv = preb[(size_t)(t + 1) * 512 + tid];  // coalesced prefetch
        }
        __syncthreads();
        // ---- phase B (threads 0..127): combine + state update ----
        if (tid < 128) {
            const float ig = actb[tid];
            const float fg = actb[132 + tid];
            const float ch = actb[264 + tid];
            const float og = actb[396 + tid];
            c = fg * c + ig * ch;
            const float h2 = og * tanh_(c);
            hbuf[tid] = h2;
            if (STORE_XH) {
                unsigned short hi = f2bf(h2);
                size_t row = (size_t)b * R + t;
                xh[row * 256 + tid] = hi;
                xh[row * 256 + 128 + tid] = f2bf(h2 - bf2f(hi));
            }
        }
        __syncthreads();
    }
    if (tid < 128) { st_h[b * 128 + tid] = hbuf[tid]; st_c[b * 128 + tid] = c; }
    if (FINAL && tid < 2) {
        float s = regb[tid];
        #pragma unroll 4
        for (int i = 0; i < 128; ++i) s = fmaf(hbuf[i], regw[i * 2 + tid], s);
        outp[b * 2 + tid] = s;   // f32 output
    }
}

// ---------- host ----------
extern "C" void kernel_launch(void* const* d_in, const int* in_sizes, int n_in,
                              void* d_out, int out_size, void* d_ws, size_t ws_size,
                              hipStream_t stream)
{
    const float* hrrp = (const float*)d_in[0];
    const float* ac   = (const float*)d_in[1];
    const float* pc   = (const float*)d_in[2];
    const float* rd   = (const float*)d_in[3];
    const float* w_amp= (const float*)d_in[4];
    const float* b_amp= (const float*)d_in[5];
    const float* w_ph = (const float*)d_in[6];
    const float* b_ph = (const float*)d_in[7];
    const float* w_g  = (const float*)d_in[8];
    const float* b_g  = (const float*)d_in[9];
    const float* w_r1 = (const float*)d_in[10];
    const float* b_r1 = (const float*)d_in[11];
    const float* w_r2 = (const float*)d_in[12];
    const float* b_r2 = (const float*)d_in[13];
    const float* w_q  = (const float*)d_in[14];
    const float* b_q  = (const float*)d_in[15];
    const float* w_k  = (const float*)d_in[16];
    const float* b_k  = (const float*)d_in[17];
    const float* w_v  = (const float*)d_in[18];
    const float* b_v  = (const float*)d_in[19];
    const float* w_o  = (const float*)d_in[20];
    const float* b_o  = (const float*)d_in[21];
    const float* w0   = (const float*)d_in[22];
    const float* b0   = (const float*)d_in[23];
    const float* gw0  = (const float*)d_in[24];
    const float* w12  = (const float*)d_in[25];
    const float* b12  = (const float*)d_in[26];
    const float* gw12 = (const float*)d_in[27];
    const float* regw = (const float*)d_in[28];
    const float* regb = (const float*)d_in[29];
    float* outp = (float*)d_out;

    const size_t need64 = 68452352ULL, need32 = 35946496ULL;
    const size_t EXTRA = 132864ULL;     // GT + WVO + e1 + e2 + bvo + e0
    int R, lg, folded;
    if      (ws_size >= need64 + EXTRA) { R = 64; lg = 6; folded = 1; }
    else if (ws_size >= need64)         { R = 64; lg = 6; folded = 0; }
    else if (ws_size >= need32 + EXTRA) { R = 32; lg = 5; folded = 1; }
    else if (ws_size >= need32)         { R = 32; lg = 5; folded = 0; }
    else return;
    const int NSEG = TT / R;
    const int MR = BB * R;

    char* ws = (char*)d_ws;
    size_t off = 0;
    float* pre = (float*)(ws + off);                   off += (size_t)MR * 512 * 4;
    unsigned short* gsh = (unsigned short*)(ws + off); off += (size_t)MR * 256 * 2;
    unsigned short* xh  = (unsigned short*)(ws + off); off += (size_t)MR * 256 * 2;
    unsigned short* xs  = (unsigned short*)(ws + off); off += (size_t)MR * 448 * 2;
    float* sh0 = (float*)(ws + off); off += 131072;
    float* sc0 = (float*)(ws + off); off += 131072;
    float* sh1 = (float*)(ws + off); off += 131072;
    float* sc1 = (float*)(ws + off); off += 131072;
    float* sh2 = (float*)(ws + off); off += 131072;
    float* sc2 = (float*)(ws + off); off += 131072;
    unsigned short* b0t = (unsigned short*)(ws + off); off += 512 * 1056 * 2;
    unsigned short* b1t = (unsigned short*)(ws + off); off += 512 * 768 * 2;
    unsigned short* b2t = (unsigned short*)(ws + off); off += 512 * 768 * 2;
    float* GT = nullptr; float* WVO = nullptr;
    float* e1p = nullptr; float* e2p = nullptr; float* bvop = nullptr; float* e0p = nullptr;
    if (folded) {
        GT   = (float*)(ws + off); off += 128 * 128 * 4;
        WVO  = (float*)(ws + off); off += 128 * 128 * 4;
        e1p  = (float*)(ws + off); off += 512;
        e2p  = (float*)(ws + off); off += 512;
        bvop = (float*)(ws + off); off += 512;
        e0p  = (float*)(ws + off); off += 256;
    }

    k_prep_b<<<512, 256, 0, stream>>>(w0, gw0, w12, gw12, b0t, b1t, b2t);
    if (folded)
        k_prep_fuse<<<128, 128, 0, stream>>>(w_q, b_q, w_k, b_k, w_v, b_v, w_o,
                                             GT, WVO, e1p, e2p, e0p, bvop);

    for (int seg = 0; seg < NSEG; ++seg) {
        const int first = (seg == 0) ? 1 : 0;
        const int tbase = seg * R;
        if (folded)
            k_gamma2<<<MR / 16, 256, 0, stream>>>(ac, pc, rd, w_amp, b_amp, w_ph, b_ph,
                                                  w_g, b_g, w_r1, b_r1, w_r2, b_r2,
                                                  GT, WVO, e1p, e2p, e0p, bvop, b_o,
                                                  gsh, R, lg, tbase);
        else
            k_gamma<<<MR / 16, 128, 0, stream>>>(ac, pc, rd, w_amp, b_amp, w_ph, b_ph,
                                                 w_g, b_g, w_r1, b_r1, w_r2, b_r2,
                                                 w_q, b_q, w_k, b_k, w_v, b_v, w_o, b_o,
                                                 gsh, R, lg, tbase);
        k_stagex<<<MR, 256, 0, stream>>>(hrrp, xs, R, lg, tbase);
        // layer 0
        k_gemm<1056><<<dim3(MR / 128, 4), 256, 0, stream>>>(xs, gsh, b0t, b0, pre);
        k_scan4<1, 0><<<BB, 1024, 0, stream>>>(pre, w0, sh0, sc0, xh,
                                               nullptr, nullptr, nullptr, first, R);
        // layer 1
        k_gemm<768><<<dim3(MR / 128, 4), 256, 0, stream>>>(xh, gsh, b1t, b12, pre);
        k_scan4<1, 0><<<BB, 1024, 0, stream>>>(pre, w12, sh1, sc1, xh,
                                               nullptr, nullptr, nullptr, first, R);
        // layer 2
        k_gemm<768><<<dim3(MR / 128, 4), 256, 0, stream>>>(xh, gsh, b2t, b12 + 512, pre);
        if (seg < NSEG - 1)
            k_scan4<0, 0><<<BB, 1024, 0, stream>>>(pre, w12 + 256 * 512, sh2, sc2,
                                                   nullptr, nullptr, nullptr, nullptr, first, R);
        else
            k_scan4<0, 1><<<BB, 1024, 0, stream>>>(pre, w12 + 256 * 512, sh2, sc2,
                                                   nullptr, outp, regw, regb, first, R);
    }
}